// Round 1
// baseline (1167.447 us; speedup 1.0000x reference)
//
#include <hip/hip_runtime.h>
#include <hip/hip_bf16.h>
#include <math.h>

// Problem dims (fixed by reference)
constexpr int B_ = 4, S_ = 4096, D_ = 2048, H_ = 1024, H2_ = 512, E_ = 8;
constexpr int CHUNK_ = 128;
constexpr int C_ = S_ / CHUNK_;          // 32 chunks
constexpr int M_ = B_ * S_;              // 16384 tokens
constexpr float TAU_ = 0.7f;

// Output layout (flat, reference return order, all read back as fp32)
constexpr int OUT_RW = 0;                        // routing_weights [B,S,E] = 131072
constexpr int OUT_EI = OUT_RW + B_ * S_ * E_;    // expert_indices [B,C] = 128 (written as float)
constexpr int OUT_CL = OUT_EI + B_ * C_;         // chunk_logits [B,C,E] = 1024
constexpr int OUT_GE = OUT_CL + B_ * C_ * E_;    // gate_entropy scalar
constexpr int OUT_UT = OUT_GE + 1;               // expert_utilization [E]
constexpr int OUT_FR = OUT_UT + E_;              // flip_rate scalar
constexpr int OUT_RC = OUT_FR + 1;               // routing_concentration scalar

// ---------------------------------------------------------------------------
// Classic fp32 SGEMM: out[M,N] = act(A[M,K] @ W[K,N] + bias[N])
// 128x128 block tile, BK=16, 256 threads, 8x8 micro-tile per thread.
// ---------------------------------------------------------------------------
template <bool RELU>
__global__ __launch_bounds__(256)
void gemm_bias_kernel(const float* __restrict__ A, const float* __restrict__ W,
                      const float* __restrict__ bias, float* __restrict__ out,
                      int Mdim, int Ndim, int Kdim)
{
    constexpr int BM = 128, BN = 128, BK = 16;
    __shared__ float As[BK][BM + 4];   // stored transposed: As[k][m]; 528B row stride (16B aligned)
    __shared__ float Bs[BK][BN + 4];

    const int tid = threadIdx.x;
    const int tx = tid & 15;           // N direction
    const int ty = tid >> 4;           // M direction
    const int blockM = blockIdx.y * BM;
    const int blockN = blockIdx.x * BN;

    // A tile load: 128 rows x 16 cols; thread -> rows (tid>>2) and (tid>>2)+64, col (tid&3)*4
    const int ar = tid >> 2;           // 0..63
    const int ac = (tid & 3) << 2;     // 0,4,8,12
    // B tile load: 16 rows x 128 cols; thread -> rows (tid>>5) and +8, col (tid&31)*4
    const int br = tid >> 5;           // 0..7
    const int bc = (tid & 31) << 2;    // 0..124

    const float* Aptr = A + (size_t)blockM * Kdim;

    float acc[8][8];
#pragma unroll
    for (int i = 0; i < 8; ++i)
#pragma unroll
        for (int j = 0; j < 8; ++j) acc[i][j] = 0.0f;

    for (int k0 = 0; k0 < Kdim; k0 += BK) {
        float4 a0 = *(const float4*)(Aptr + (size_t)ar * Kdim + k0 + ac);
        float4 a1 = *(const float4*)(Aptr + (size_t)(ar + 64) * Kdim + k0 + ac);
        float4 b0 = *(const float4*)(W + (size_t)(k0 + br) * Ndim + blockN + bc);
        float4 b1 = *(const float4*)(W + (size_t)(k0 + br + 8) * Ndim + blockN + bc);
        __syncthreads();   // prior iteration's LDS reads done
        As[ac + 0][ar] = a0.x; As[ac + 1][ar] = a0.y; As[ac + 2][ar] = a0.z; As[ac + 3][ar] = a0.w;
        As[ac + 0][ar + 64] = a1.x; As[ac + 1][ar + 64] = a1.y; As[ac + 2][ar + 64] = a1.z; As[ac + 3][ar + 64] = a1.w;
        *(float4*)&Bs[br][bc] = b0;
        *(float4*)&Bs[br + 8][bc] = b1;
        __syncthreads();
#pragma unroll
        for (int kk = 0; kk < BK; ++kk) {
            float av[8], bv[8];
            *(float4*)&av[0] = *(const float4*)&As[kk][ty * 8];
            *(float4*)&av[4] = *(const float4*)&As[kk][ty * 8 + 4];
            *(float4*)&bv[0] = *(const float4*)&Bs[kk][tx * 8];
            *(float4*)&bv[4] = *(const float4*)&Bs[kk][tx * 8 + 4];
#pragma unroll
            for (int i = 0; i < 8; ++i)
#pragma unroll
                for (int j = 0; j < 8; ++j)
                    acc[i][j] = fmaf(av[i], bv[j], acc[i][j]);
        }
    }

    const int gm = blockM + ty * 8;
    const int gn = blockN + tx * 8;
    float bv[8];
#pragma unroll
    for (int j = 0; j < 8; ++j) bv[j] = bias[gn + j];
#pragma unroll
    for (int i = 0; i < 8; ++i) {
        float o[8];
#pragma unroll
        for (int j = 0; j < 8; ++j) {
            float v = acc[i][j] + bv[j];
            o[j] = RELU ? fmaxf(v, 0.0f) : v;
        }
        float* dst = out + (size_t)(gm + i) * Ndim + gn;
        *(float4*)(dst + 0) = *(float4*)&o[0];
        *(float4*)(dst + 4) = *(float4*)&o[4];
    }
}

// ---------------------------------------------------------------------------
// Fused final layer + chunk mean: one block per (b,c) chunk.
// tok_logits = h2 @ w3 + b3 ; chunk_logits = mean over 128 tokens ; argmax.
// ---------------------------------------------------------------------------
__global__ __launch_bounds__(256)
void chunk_logits_kernel(const float* __restrict__ h2, const float* __restrict__ w3,
                         const float* __restrict__ b3,
                         float* __restrict__ cl_out,   // d_out + OUT_CL
                         float* __restrict__ cl_ws,    // ws copy for finalize
                         int* __restrict__ top_ws)     // per-chunk argmax
{
    __shared__ float w3s[H2_][E_];        // 16 KB
    __shared__ float red[256][E_ + 1];    // padded: 9 coprime with 32 -> conflict-free

    const int bc = blockIdx.x;            // 0..B*C-1
    const int tid = threadIdx.x;

    for (int i = tid; i < H2_ * E_; i += 256) w3s[i / E_][i % E_] = w3[i];
    __syncthreads();

    const int tok = tid & 127;
    const int half = tid >> 7;            // split K in two halves across thread pairs
    const float* hrow = h2 + ((size_t)bc * CHUNK_ + tok) * H2_ + half * (H2_ / 2);

    float acc[E_];
#pragma unroll
    for (int e = 0; e < E_; ++e) acc[e] = 0.0f;

    for (int k4 = 0; k4 < (H2_ / 2) / 4; ++k4) {
        float4 hv = *(const float4*)(hrow + k4 * 4);
        const int kb = half * (H2_ / 2) + k4 * 4;
        const float* hvp = (const float*)&hv;
#pragma unroll
        for (int q = 0; q < 4; ++q) {
            float h = hvp[q];
            const float* wr = &w3s[kb + q][0];
#pragma unroll
            for (int e = 0; e < E_; ++e) acc[e] = fmaf(h, wr[e], acc[e]);
        }
    }
#pragma unroll
    for (int e = 0; e < E_; ++e) red[tid][e] = acc[e];
    __syncthreads();
    for (int s = 128; s > 0; s >>= 1) {
        if (tid < s) {
#pragma unroll
            for (int e = 0; e < E_; ++e) red[tid][e] += red[tid + s][e];
        }
        __syncthreads();
    }
    if (tid < E_) {
        float v = red[0][tid] * (1.0f / CHUNK_) + b3[tid];
        red[0][tid] = v;                 // keep in LDS for argmax
        cl_out[bc * E_ + tid] = v;
        cl_ws[bc * E_ + tid] = v;
    }
    __syncthreads();
    if (tid == 0) {
        int best = 0;
        float bvv = red[0][0];
        for (int e = 1; e < E_; ++e) {
            float v = red[0][e];
            if (v > bvv) { bvv = v; best = e; }   // first-max tiebreak == numpy argmax
        }
        top_ws[bc] = best;
    }
}

// ---------------------------------------------------------------------------
// Sequential hysteresis scan + all stats. Single block, 128 threads.
// NOTE: prev_expert_indices is UNUSED by the reference (scan init = zeros,
// is_first overrides chunk 0), so it's unused here too.
// ---------------------------------------------------------------------------
__global__ __launch_bounds__(128)
void finalize_kernel(const float* __restrict__ cl_ws, const int* __restrict__ top_ws,
                     float* __restrict__ out, int* __restrict__ experts_ws)
{
    __shared__ float cl[B_ * C_][E_];
    __shared__ int tops[B_ * C_];
    __shared__ int finals[B_ * C_];
    __shared__ int flips[B_];
    __shared__ float ent[B_ * C_];

    const int tid = threadIdx.x;  // 128
    for (int i = tid; i < B_ * C_ * E_; i += 128) cl[i / E_][i % E_] = cl_ws[i];
    tops[tid] = top_ws[tid];
    __syncthreads();

    if (tid < B_) {
        const int b = tid;
        int prev = 0, fl = 0;
        for (int c = 0; c < C_; ++c) {
            const int t = tops[b * C_ + c];
            int fin;
            if (c == 0) {
                fin = t;
            } else {
                float cur = cl[b * C_ + c][t];
                float pv = cl[b * C_ + c][prev];
                bool sw = (cur - pv) > TAU_;
                if (sw) fl++;
                fin = sw ? t : prev;
            }
            finals[b * C_ + c] = fin;
            prev = fin;
        }
        flips[b] = fl;
    }

    // per-chunk softmax entropy (one chunk per thread)
    {
        float m = cl[tid][0];
        for (int e = 1; e < E_; ++e) m = fmaxf(m, cl[tid][e]);
        float p[E_], s = 0.0f;
        for (int e = 0; e < E_; ++e) { p[e] = expf(cl[tid][e] - m); s += p[e]; }
        float inv = 1.0f / s, h = 0.0f;
        for (int e = 0; e < E_; ++e) { float pe = p[e] * inv; h -= pe * logf(pe + 1e-8f); }
        ent[tid] = h;
    }
    __syncthreads();

    if (tid == 0) {
        float esum = 0.0f;
        for (int i = 0; i < B_ * C_; ++i) esum += ent[i];
        out[OUT_GE] = esum / (float)(B_ * C_);

        int cnt[E_];
        for (int e = 0; e < E_; ++e) cnt[e] = 0;
        for (int i = 0; i < B_ * C_; ++i) cnt[finals[i]]++;
        float n2 = 0.0f;
        for (int e = 0; e < E_; ++e) {
            float u = (float)cnt[e] / (float)(B_ * C_);
            out[OUT_UT + e] = u;
            n2 += u * u;
        }
        int totfl = flips[0] + flips[1] + flips[2] + flips[3];
        out[OUT_FR] = (float)totfl / (float)(B_ * (C_ - 1));
        out[OUT_RC] = sqrtf(n2);
    }

    out[OUT_EI + tid] = (float)finals[tid];
    experts_ws[tid] = finals[tid];
}

// ---------------------------------------------------------------------------
// routing_weights: one-hot broadcast per chunk. One thread per token.
// ---------------------------------------------------------------------------
__global__ __launch_bounds__(256)
void routing_weights_kernel(const int* __restrict__ experts_ws, float* __restrict__ out)
{
    const int tok = blockIdx.x * 256 + threadIdx.x;   // 0..16383
    const int b = tok >> 12;                          // /4096
    const int c = (tok & (S_ - 1)) >> 7;              // within-seq /128
    const int e = experts_ws[b * C_ + c];
    float4 v0 = make_float4(e == 0 ? 1.f : 0.f, e == 1 ? 1.f : 0.f,
                            e == 2 ? 1.f : 0.f, e == 3 ? 1.f : 0.f);
    float4 v1 = make_float4(e == 4 ? 1.f : 0.f, e == 5 ? 1.f : 0.f,
                            e == 6 ? 1.f : 0.f, e == 7 ? 1.f : 0.f);
    float4* dst = (float4*)(out + (size_t)tok * E_);
    dst[0] = v0;
    dst[1] = v1;
}

// ---------------------------------------------------------------------------
extern "C" void kernel_launch(void* const* d_in, const int* in_sizes, int n_in,
                              void* d_out, int out_size, void* d_ws, size_t ws_size,
                              hipStream_t stream)
{
    const float* x  = (const float*)d_in[0];
    // d_in[1] = prev_expert_indices: unused by the reference computation
    const float* w1 = (const float*)d_in[2];
    const float* b1 = (const float*)d_in[3];
    const float* w2 = (const float*)d_in[4];
    const float* b2 = (const float*)d_in[5];
    const float* w3 = (const float*)d_in[6];
    const float* b3 = (const float*)d_in[7];
    float* out = (float*)d_out;

    // workspace layout (fp32): h1 64MB | h2 32MB | cl 4KB | top 512B | experts 512B
    float* h1 = (float*)d_ws;
    float* h2 = h1 + (size_t)M_ * H_;
    float* cl_ws = h2 + (size_t)M_ * H2_;
    int* top_ws = (int*)(cl_ws + B_ * C_ * E_);
    int* experts_ws = top_ws + B_ * C_;

    dim3 blk(256);
    // GEMM1: h1 = relu(x @ w1 + b1)   [16384,2048]x[2048,1024]
    gemm_bias_kernel<true><<<dim3(H_ / 128, M_ / 128), blk, 0, stream>>>(x, w1, b1, h1, M_, H_, D_);
    // GEMM2: h2 = relu(h1 @ w2 + b2)  [16384,1024]x[1024,512]
    gemm_bias_kernel<true><<<dim3(H2_ / 128, M_ / 128), blk, 0, stream>>>(h1, w2, b2, h2, M_, H2_, H_);
    // chunk logits + argmax
    chunk_logits_kernel<<<dim3(B_ * C_), blk, 0, stream>>>(h2, w3, b3, out + OUT_CL, cl_ws, top_ws);
    // hysteresis scan + stats
    finalize_kernel<<<dim3(1), dim3(128), 0, stream>>>(cl_ws, top_ws, out, experts_ws);
    // one-hot routing weights
    routing_weights_kernel<<<dim3(M_ / 256), blk, 0, stream>>>(experts_ws, out + OUT_RW);
}

// Round 2
// 536.454 us; speedup vs baseline: 2.1762x; 2.1762x over previous
//
#include <hip/hip_runtime.h>
#include <hip/hip_bf16.h>
#include <math.h>

typedef _Float16 half_t;
typedef __attribute__((ext_vector_type(4))) _Float16 half4v;
typedef __attribute__((ext_vector_type(8))) _Float16 half8v;
typedef __attribute__((ext_vector_type(4))) float floatx4;

constexpr int B_ = 4, S_ = 4096, D_ = 2048, H_ = 1024, H2_ = 512, E_ = 8;
constexpr int CHUNK_ = 128;
constexpr int C_ = S_ / CHUNK_;
constexpr int M_ = B_ * S_;
constexpr float TAU_ = 0.7f;
constexpr float LO_SCALE = 2048.0f;
constexpr float LO_INV = 1.0f / 2048.0f;

constexpr int OUT_RW = 0;
constexpr int OUT_EI = OUT_RW + B_ * S_ * E_;
constexpr int OUT_CL = OUT_EI + B_ * C_;
constexpr int OUT_GE = OUT_CL + B_ * C_ * E_;
constexpr int OUT_UT = OUT_GE + 1;
constexpr int OUT_FR = OUT_UT + E_;
constexpr int OUT_RC = OUT_FR + 1;

__global__ __launch_bounds__(256)
void convert_split_kernel(const float* __restrict__ src, half_t* __restrict__ hi,
                          half_t* __restrict__ lo, int n4)
{
    const int i = blockIdx.x * 256 + threadIdx.x;
    if (i >= n4) return;
    const float4 v = ((const float4*)src)[i];
    half4v h, l;
    h.x = (half_t)v.x; h.y = (half_t)v.y; h.z = (half_t)v.z; h.w = (half_t)v.w;
    l.x = (half_t)((v.x - (float)h.x) * LO_SCALE);
    l.y = (half_t)((v.y - (float)h.y) * LO_SCALE);
    l.z = (half_t)((v.z - (float)h.z) * LO_SCALE);
    l.w = (half_t)((v.w - (float)h.w) * LO_SCALE);
    ((half4v*)hi)[i] = h;
    ((half4v*)lo)[i] = l;
}

__global__ __launch_bounds__(256)
void transpose_split_kernel(const float* __restrict__ W, half_t* __restrict__ hi,
                            half_t* __restrict__ lo, int K, int N)
{
    __shared__ float tile[32][33];
    const int tx = threadIdx.x & 31;
    const int ty = threadIdx.x >> 5;
    const int k0 = blockIdx.y * 32;
    const int n0 = blockIdx.x * 32;
#pragma unroll
    for (int r = 0; r < 4; ++r)
        tile[ty + r * 8][tx] = W[(size_t)(k0 + ty + r * 8) * N + n0 + tx];
    __syncthreads();
#pragma unroll
    for (int r = 0; r < 4; ++r) {
        const float v = tile[tx][ty + r * 8];
        const half_t h = (half_t)v;
        const size_t off = (size_t)(n0 + ty + r * 8) * K + k0 + tx;
        hi[off] = h;
        lo[off] = (half_t)((v - (float)h) * LO_SCALE);
    }
}

// f16x3 split-precision MFMA GEMM. relu is ALWAYS applied (both MLP layers are
// relu'd in the reference). SPLIT_OUT selects output format: 1 -> f16 hi/lo
// pair (feeds next GEMM), 0 -> fp32.
template <int SPLIT_OUT>
__global__ __launch_bounds__(256, 2)
void gemm_f16x3_kernel(const half_t* __restrict__ Ah, const half_t* __restrict__ Al,
                       const half_t* __restrict__ BTh, const half_t* __restrict__ BTl,
                       const float* __restrict__ bias,
                       float* __restrict__ outf, half_t* __restrict__ outh,
                       half_t* __restrict__ outl, int Ndim, int Kdim)
{
    constexpr int BK = 32;
    __shared__ __align__(16) half_t sAh[128 * BK];
    __shared__ __align__(16) half_t sAl[128 * BK];
    __shared__ __align__(16) half_t sBh[128 * BK];
    __shared__ __align__(16) half_t sBl[128 * BK];

    const int tid = threadIdx.x;
    const int lane = tid & 63;
    const int wave = tid >> 6;
    const int wm = (wave & 1) * 64;
    const int wn = (wave >> 1) * 64;
    const long blockM = (long)blockIdx.y * 128;
    const long blockN = (long)blockIdx.x * 128;

    floatx4 acc_h[4][4], acc_c[4][4];
#pragma unroll
    for (int i = 0; i < 4; ++i)
#pragma unroll
        for (int j = 0; j < 4; ++j) {
            acc_h[i][j] = (floatx4){0.f, 0.f, 0.f, 0.f};
            acc_c[i][j] = (floatx4){0.f, 0.f, 0.f, 0.f};
        }

    const int srow = tid >> 2;
    const int skoff = (tid & 3) * 8;
    const int ldsoff = srow * BK + skoff;   // == tid*8 elements == tid*16 bytes

    const int fr = lane & 15;
    const int fq = (lane >> 4) * 8;

    for (int k0 = 0; k0 < Kdim; k0 += BK) {
        __syncthreads();
#pragma unroll
        for (int p = 0; p < 2; ++p) {
            const int row = srow + p * 64;
            const size_t aoff = (size_t)(blockM + row) * Kdim + k0 + skoff;
            const size_t boff = (size_t)(blockN + row) * Kdim + k0 + skoff;
            const int loff = ldsoff + p * 2048;
            __builtin_amdgcn_global_load_lds(
                (const __attribute__((address_space(1))) void*)(Ah + aoff),
                (__attribute__((address_space(3))) void*)(sAh + loff), 16, 0, 0);
            __builtin_amdgcn_global_load_lds(
                (const __attribute__((address_space(1))) void*)(Al + aoff),
                (__attribute__((address_space(3))) void*)(sAl + loff), 16, 0, 0);
            __builtin_amdgcn_global_load_lds(
                (const __attribute__((address_space(1))) void*)(BTh + boff),
                (__attribute__((address_space(3))) void*)(sBh + loff), 16, 0, 0);
            __builtin_amdgcn_global_load_lds(
                (const __attribute__((address_space(1))) void*)(BTl + boff),
                (__attribute__((address_space(3))) void*)(sBl + loff), 16, 0, 0);
        }
        __syncthreads();

        half8v fah[4], fal[4], fbh[4], fbl[4];
#pragma unroll
        for (int t = 0; t < 4; ++t) {
            fah[t] = *(const half8v*)(sAh + (wm + t * 16 + fr) * BK + fq);
            fal[t] = *(const half8v*)(sAl + (wm + t * 16 + fr) * BK + fq);
            fbh[t] = *(const half8v*)(sBh + (wn + t * 16 + fr) * BK + fq);
            fbl[t] = *(const half8v*)(sBl + (wn + t * 16 + fr) * BK + fq);
        }
#pragma unroll
        for (int i = 0; i < 4; ++i)
#pragma unroll
            for (int j = 0; j < 4; ++j) {
                acc_h[i][j] = __builtin_amdgcn_mfma_f32_16x16x32_f16(fah[i], fbh[j], acc_h[i][j], 0, 0, 0);
                acc_c[i][j] = __builtin_amdgcn_mfma_f32_16x16x32_f16(fah[i], fbl[j], acc_c[i][j], 0, 0, 0);
                acc_c[i][j] = __builtin_amdgcn_mfma_f32_16x16x32_f16(fal[i], fbh[j], acc_c[i][j], 0, 0, 0);
            }
    }

    const int orow = (lane >> 4) * 4;
    const int ocol = lane & 15;
#pragma unroll
    for (int j = 0; j < 4; ++j) {
        const long gn = blockN + wn + j * 16 + ocol;
        const float bj = bias[gn];
#pragma unroll
        for (int i = 0; i < 4; ++i) {
#pragma unroll
            for (int r = 0; r < 4; ++r) {
                float v = acc_h[i][j][r] + acc_c[i][j][r] * LO_INV + bj;
                v = fmaxf(v, 0.0f);   // relu (both MLP layers)
                const size_t off = (size_t)(blockM + wm + i * 16 + orow + r) * Ndim + gn;
                if (SPLIT_OUT) {
                    const half_t h = (half_t)v;
                    outh[off] = h;
                    outl[off] = (half_t)((v - (float)h) * LO_SCALE);
                } else {
                    outf[off] = v;
                }
            }
        }
    }
}

__global__ __launch_bounds__(256)
void chunk_logits_kernel(const float* __restrict__ h2, const float* __restrict__ w3,
                         const float* __restrict__ b3,
                         float* __restrict__ cl_out, float* __restrict__ cl_ws,
                         int* __restrict__ top_ws)
{
    __shared__ float w3s[H2_][E_];
    __shared__ float red[256][E_ + 1];

    const int bc = blockIdx.x;
    const int tid = threadIdx.x;

    for (int i = tid; i < H2_ * E_; i += 256) w3s[i / E_][i % E_] = w3[i];
    __syncthreads();

    const int tok = tid & 127;
    const int half_ = tid >> 7;
    const float* hrow = h2 + ((size_t)bc * CHUNK_ + tok) * H2_ + half_ * (H2_ / 2);

    float acc[E_];
#pragma unroll
    for (int e = 0; e < E_; ++e) acc[e] = 0.0f;

    for (int k4 = 0; k4 < (H2_ / 2) / 4; ++k4) {
        float4 hv = *(const float4*)(hrow + k4 * 4);
        const int kb = half_ * (H2_ / 2) + k4 * 4;
        const float* hvp = (const float*)&hv;
#pragma unroll
        for (int q = 0; q < 4; ++q) {
            float h = hvp[q];
            const float* wr = &w3s[kb + q][0];
#pragma unroll
            for (int e = 0; e < E_; ++e) acc[e] = fmaf(h, wr[e], acc[e]);
        }
    }
#pragma unroll
    for (int e = 0; e < E_; ++e) red[tid][e] = acc[e];
    __syncthreads();
    for (int s = 128; s > 0; s >>= 1) {
        if (tid < s) {
#pragma unroll
            for (int e = 0; e < E_; ++e) red[tid][e] += red[tid + s][e];
        }
        __syncthreads();
    }
    if (tid < E_) {
        float v = red[0][tid] * (1.0f / CHUNK_) + b3[tid];
        red[0][tid] = v;
        cl_out[bc * E_ + tid] = v;
        cl_ws[bc * E_ + tid] = v;
    }
    __syncthreads();
    if (tid == 0) {
        int best = 0;
        float bvv = red[0][0];
        for (int e = 1; e < E_; ++e) {
            float v = red[0][e];
            if (v > bvv) { bvv = v; best = e; }
        }
        top_ws[bc] = best;
    }
}

__global__ __launch_bounds__(128)
void finalize_kernel(const float* __restrict__ cl_ws, const int* __restrict__ top_ws,
                     float* __restrict__ out, int* __restrict__ experts_ws)
{
    __shared__ float cl[B_ * C_][E_];
    __shared__ int tops[B_ * C_];
    __shared__ int finals[B_ * C_];
    __shared__ int flips[B_];
    __shared__ float ent[B_ * C_];

    const int tid = threadIdx.x;
    for (int i = tid; i < B_ * C_ * E_; i += 128) cl[i / E_][i % E_] = cl_ws[i];
    tops[tid] = top_ws[tid];
    __syncthreads();

    if (tid < B_) {
        const int b = tid;
        int prev = 0, fl = 0;
        for (int c = 0; c < C_; ++c) {
            const int t = tops[b * C_ + c];
            int fin;
            if (c == 0) {
                fin = t;
            } else {
                float cur = cl[b * C_ + c][t];
                float pv = cl[b * C_ + c][prev];
                bool sw = (cur - pv) > TAU_;
                if (sw) fl++;
                fin = sw ? t : prev;
            }
            finals[b * C_ + c] = fin;
            prev = fin;
        }
        flips[b] = fl;
    }

    {
        float m = cl[tid][0];
        for (int e = 1; e < E_; ++e) m = fmaxf(m, cl[tid][e]);
        float p[E_], s = 0.0f;
        for (int e = 0; e < E_; ++e) { p[e] = expf(cl[tid][e] - m); s += p[e]; }
        float inv = 1.0f / s, h = 0.0f;
        for (int e = 0; e < E_; ++e) { float pe = p[e] * inv; h -= pe * logf(pe + 1e-8f); }
        ent[tid] = h;
    }
    __syncthreads();

    if (tid == 0) {
        float esum = 0.0f;
        for (int i = 0; i < B_ * C_; ++i) esum += ent[i];
        out[OUT_GE] = esum / (float)(B_ * C_);

        int cnt[E_];
        for (int e = 0; e < E_; ++e) cnt[e] = 0;
        for (int i = 0; i < B_ * C_; ++i) cnt[finals[i]]++;
        float n2 = 0.0f;
        for (int e = 0; e < E_; ++e) {
            float u = (float)cnt[e] / (float)(B_ * C_);
            out[OUT_UT + e] = u;
            n2 += u * u;
        }
        int totfl = flips[0] + flips[1] + flips[2] + flips[3];
        out[OUT_FR] = (float)totfl / (float)(B_ * (C_ - 1));
        out[OUT_RC] = sqrtf(n2);
    }

    out[OUT_EI + tid] = (float)finals[tid];
    experts_ws[tid] = finals[tid];
}

__global__ __launch_bounds__(256)
void routing_weights_kernel(const int* __restrict__ experts_ws, float* __restrict__ out)
{
    const int tok = blockIdx.x * 256 + threadIdx.x;
    const int b = tok >> 12;
    const int c = (tok & (S_ - 1)) >> 7;
    const int e = experts_ws[b * C_ + c];
    float4 v0 = make_float4(e == 0 ? 1.f : 0.f, e == 1 ? 1.f : 0.f,
                            e == 2 ? 1.f : 0.f, e == 3 ? 1.f : 0.f);
    float4 v1 = make_float4(e == 4 ? 1.f : 0.f, e == 5 ? 1.f : 0.f,
                            e == 6 ? 1.f : 0.f, e == 7 ? 1.f : 0.f);
    float4* dst = (float4*)(out + (size_t)tok * E_);
    dst[0] = v0;
    dst[1] = v1;
}

extern "C" void kernel_launch(void* const* d_in, const int* in_sizes, int n_in,
                              void* d_out, int out_size, void* d_ws, size_t ws_size,
                              hipStream_t stream)
{
    const float* x  = (const float*)d_in[0];
    const float* w1 = (const float*)d_in[2];
    const float* b1 = (const float*)d_in[3];
    const float* w2 = (const float*)d_in[4];
    const float* b2 = (const float*)d_in[5];
    const float* w3 = (const float*)d_in[6];
    const float* b3 = (const float*)d_in[7];
    float* out = (float*)d_out;

    half_t* xh   = (half_t*)d_ws;                    // 64 MB
    half_t* xl   = xh + (size_t)M_ * D_;             // 64 MB
    half_t* w1th = xl + (size_t)M_ * D_;             // 4 MB
    half_t* w1tl = w1th + (size_t)H_ * D_;           // 4 MB
    half_t* h1h  = w1tl + (size_t)H_ * D_;           // 32 MB
    half_t* h1l  = h1h + (size_t)M_ * H_;            // 32 MB
    half_t* w2th = h1l + (size_t)M_ * H_;            // 1 MB
    half_t* w2tl = w2th + (size_t)H2_ * H_;          // 1 MB
    float*  cl_ws = (float*)(w2tl + (size_t)H2_ * H_);
    int* top_ws = (int*)(cl_ws + B_ * C_ * E_);
    int* experts_ws = top_ws + B_ * C_;
    float* h2 = (float*)xh;  // alias: x split dead after GEMM1

    convert_split_kernel<<<dim3((M_ * (D_ / 4)) / 256), dim3(256), 0, stream>>>(
        x, xh, xl, M_ * (D_ / 4));
    transpose_split_kernel<<<dim3(H_ / 32, D_ / 32), dim3(256), 0, stream>>>(w1, w1th, w1tl, D_, H_);
    transpose_split_kernel<<<dim3(H2_ / 32, H_ / 32), dim3(256), 0, stream>>>(w2, w2th, w2tl, H_, H2_);
    gemm_f16x3_kernel<1><<<dim3(H_ / 128, M_ / 128), dim3(256), 0, stream>>>(
        xh, xl, w1th, w1tl, b1, nullptr, h1h, h1l, H_, D_);
    gemm_f16x3_kernel<0><<<dim3(H2_ / 128, M_ / 128), dim3(256), 0, stream>>>(
        h1h, h1l, w2th, w2tl, b2, h2, nullptr, nullptr, H2_, H_);
    chunk_logits_kernel<<<dim3(B_ * C_), dim3(256), 0, stream>>>(h2, w3, b3,
                                                                 out + OUT_CL, cl_ws, top_ws);
    finalize_kernel<<<dim3(1), dim3(128), 0, stream>>>(cl_ws, top_ws, out, experts_ws);
    routing_weights_kernel<<<dim3(M_ / 256), dim3(256), 0, stream>>>(experts_ws, out + OUT_RW);
}

// Round 3
// 516.571 us; speedup vs baseline: 2.2600x; 1.0385x over previous
//
#include <hip/hip_runtime.h>
#include <math.h>

typedef _Float16 half_t;
typedef __attribute__((ext_vector_type(4))) _Float16 half4v;
typedef __attribute__((ext_vector_type(8))) _Float16 half8v;
typedef __attribute__((ext_vector_type(4))) float floatx4;

constexpr int B_ = 4, S_ = 4096, D_ = 2048, H_ = 1024, H2_ = 512, E_ = 8;
constexpr int CHUNK_ = 128;
constexpr int C_ = S_ / CHUNK_;          // 32
constexpr int M_ = B_ * S_;              // 16384
constexpr float TAU_ = 0.7f;
// Weights pre-scaled x64 so their f16 residuals are normal-range; outputs
// descaled by 1/64 in the epilogue. Lets hi*hi + hi*lo + lo*hi share ONE
// fp32 accumulator (64 AGPRs instead of 128 -> 3 waves/SIMD).
constexpr float WSCALE = 64.0f, OSCALE = 1.0f / 64.0f;

constexpr int OUT_RW = 0;
constexpr int OUT_EI = OUT_RW + B_ * S_ * E_;
constexpr int OUT_CL = OUT_EI + B_ * C_;
constexpr int OUT_GE = OUT_CL + B_ * C_ * E_;
constexpr int OUT_UT = OUT_GE + 1;
constexpr int OUT_FR = OUT_UT + E_;
constexpr int OUT_RC = OUT_FR + 1;

// ---------------------------------------------------------------------------
// Split fp32 x -> f16 hi + raw residual lo (x values O(1): residuals of
// |x|>0.125 are f16-normal; smaller ones bounded by 6e-5 abs -> negligible).
// ---------------------------------------------------------------------------
__global__ __launch_bounds__(256)
void convert_split_kernel(const float* __restrict__ src, half_t* __restrict__ hi,
                          half_t* __restrict__ lo, int n4)
{
    const int i = blockIdx.x * 256 + threadIdx.x;
    if (i >= n4) return;
    const float4 v = ((const float4*)src)[i];
    half4v h, l;
    h.x = (half_t)v.x; h.y = (half_t)v.y; h.z = (half_t)v.z; h.w = (half_t)v.w;
    l.x = (half_t)(v.x - (float)h.x);
    l.y = (half_t)(v.y - (float)h.y);
    l.z = (half_t)(v.z - (float)h.z);
    l.w = (half_t)(v.w - (float)h.w);
    ((half4v*)hi)[i] = h;
    ((half4v*)lo)[i] = l;
}

// ---------------------------------------------------------------------------
// Transpose W [K,N] fp32 -> WT hi/lo f16 [N,K], pre-scaled x64.
// ---------------------------------------------------------------------------
__global__ __launch_bounds__(256)
void transpose_split_kernel(const float* __restrict__ W, half_t* __restrict__ hi,
                            half_t* __restrict__ lo, int K, int N)
{
    __shared__ float tile[32][33];
    const int tx = threadIdx.x & 31;
    const int ty = threadIdx.x >> 5;
    const int k0 = blockIdx.y * 32;
    const int n0 = blockIdx.x * 32;
#pragma unroll
    for (int r = 0; r < 4; ++r)
        tile[ty + r * 8][tx] = W[(size_t)(k0 + ty + r * 8) * N + n0 + tx];
    __syncthreads();
#pragma unroll
    for (int r = 0; r < 4; ++r) {
        const float v = tile[tx][ty + r * 8] * WSCALE;
        const half_t h = (half_t)v;
        const size_t off = (size_t)(n0 + ty + r * 8) * K + k0 + tx;
        hi[off] = h;
        lo[off] = (half_t)(v - (float)h);
    }
}

// ---------------------------------------------------------------------------
// GEMM1: h1 = relu(x @ w1 + b1), split f16 out. 128x128 tile, BK=32,
// single-accumulator f16x3, global_load_lds(16B), XCD-swizzled.
// ---------------------------------------------------------------------------
__global__ __launch_bounds__(256, 3)
void gemm1_kernel(const half_t* __restrict__ Ah, const half_t* __restrict__ Al,
                  const half_t* __restrict__ BTh, const half_t* __restrict__ BTl,
                  const float* __restrict__ bias,
                  half_t* __restrict__ outh, half_t* __restrict__ outl)
{
    constexpr int KD = D_, ND = H_, BK = 32;
    __shared__ __align__(16) half_t sAh[128 * BK];
    __shared__ __align__(16) half_t sAl[128 * BK];
    __shared__ __align__(16) half_t sBh[128 * BK];
    __shared__ __align__(16) half_t sBl[128 * BK];

    const int tid = threadIdx.x;
    const int lane = tid & 63;
    const int wave = tid >> 6;
    const int wm = (wave & 1) * 64;
    const int wn = (wave >> 1) * 64;
    // XCD swizzle: grid (8,128), dispatch d=y*8+x -> xcd=d%8=x. Give each XCD
    // an M-stripe; concurrent blocks within an XCD share a row-block (A in L2).
    const int rowBlk = blockIdx.x * 16 + (blockIdx.y >> 3);
    const int colBlk = blockIdx.y & 7;
    const long blockM = (long)rowBlk * 128;
    const long blockN = (long)colBlk * 128;

    floatx4 acc[4][4];
#pragma unroll
    for (int i = 0; i < 4; ++i)
#pragma unroll
        for (int j = 0; j < 4; ++j) acc[i][j] = (floatx4){0.f, 0.f, 0.f, 0.f};

    const int srow = tid >> 2;
    const int skoff = (tid & 3) * 8;
    const int ldsoff = srow * BK + skoff;
    const int fr = lane & 15;
    const int fq = (lane >> 4) * 8;

    for (int k0 = 0; k0 < KD; k0 += BK) {
        __syncthreads();
#pragma unroll
        for (int p = 0; p < 2; ++p) {
            const int row = srow + p * 64;
            const size_t aoff = (size_t)(blockM + row) * KD + k0 + skoff;
            const size_t boff = (size_t)(blockN + row) * KD + k0 + skoff;
            const int loff = ldsoff + p * 2048;
            __builtin_amdgcn_global_load_lds(
                (const __attribute__((address_space(1))) void*)(Ah + aoff),
                (__attribute__((address_space(3))) void*)(sAh + loff), 16, 0, 0);
            __builtin_amdgcn_global_load_lds(
                (const __attribute__((address_space(1))) void*)(Al + aoff),
                (__attribute__((address_space(3))) void*)(sAl + loff), 16, 0, 0);
            __builtin_amdgcn_global_load_lds(
                (const __attribute__((address_space(1))) void*)(BTh + boff),
                (__attribute__((address_space(3))) void*)(sBh + loff), 16, 0, 0);
            __builtin_amdgcn_global_load_lds(
                (const __attribute__((address_space(1))) void*)(BTl + boff),
                (__attribute__((address_space(3))) void*)(sBl + loff), 16, 0, 0);
        }
        __syncthreads();

        half8v fbh[4], fbl[4];
#pragma unroll
        for (int t = 0; t < 4; ++t) {
            fbh[t] = *(const half8v*)(sBh + (wn + t * 16 + fr) * BK + fq);
            fbl[t] = *(const half8v*)(sBl + (wn + t * 16 + fr) * BK + fq);
        }
#pragma unroll
        for (int i = 0; i < 4; ++i) {
            half8v fah = *(const half8v*)(sAh + (wm + i * 16 + fr) * BK + fq);
            half8v fal = *(const half8v*)(sAl + (wm + i * 16 + fr) * BK + fq);
#pragma unroll
            for (int j = 0; j < 4; ++j) {
                acc[i][j] = __builtin_amdgcn_mfma_f32_16x16x32_f16(fah, fbh[j], acc[i][j], 0, 0, 0);
                acc[i][j] = __builtin_amdgcn_mfma_f32_16x16x32_f16(fah, fbl[j], acc[i][j], 0, 0, 0);
                acc[i][j] = __builtin_amdgcn_mfma_f32_16x16x32_f16(fal, fbh[j], acc[i][j], 0, 0, 0);
            }
        }
    }

    const int orow = (lane >> 4) * 4;
    const int ocol = lane & 15;
#pragma unroll
    for (int j = 0; j < 4; ++j) {
        const long gn = blockN + wn + j * 16 + ocol;
        const float bj = bias[gn];
#pragma unroll
        for (int i = 0; i < 4; ++i) {
#pragma unroll
            for (int r = 0; r < 4; ++r) {
                float v = fmaxf(acc[i][j][r] * OSCALE + bj, 0.0f);
                const size_t off = (size_t)(blockM + wm + i * 16 + orow + r) * ND + gn;
                const half_t h = (half_t)v;
                outh[off] = h;
                outl[off] = (half_t)(v - (float)h);
            }
        }
    }
}

// ---------------------------------------------------------------------------
// GEMM2 fused: relu(h1 @ w2 + b2) @ w3, chunk-summed. Each 128-row block is
// exactly one chunk; per-thread colsum * w3 row, wave shuffle-reduce, then
// device-scope atomicAdd into cl_acc[bc][e]. h2 never materialized.
// ---------------------------------------------------------------------------
__global__ __launch_bounds__(256, 3)
void gemm2_fused_kernel(const half_t* __restrict__ Ah, const half_t* __restrict__ Al,
                        const half_t* __restrict__ BTh, const half_t* __restrict__ BTl,
                        const float* __restrict__ bias, const float* __restrict__ w3,
                        float* __restrict__ cl_acc)
{
    constexpr int KD = H_, ND = H2_, BK = 32;
    __shared__ __align__(16) half_t sAh[128 * BK];
    __shared__ __align__(16) half_t sAl[128 * BK];
    __shared__ __align__(16) half_t sBh[128 * BK];
    __shared__ __align__(16) half_t sBl[128 * BK];

    const int tid = threadIdx.x;
    const int lane = tid & 63;
    const int wave = tid >> 6;
    const int wm = (wave & 1) * 64;
    const int wn = (wave >> 1) * 64;
    // XCD swizzle: grid (4,128), d=y*4+x, xcd=d%8.
    const int d = blockIdx.y * 4 + blockIdx.x;
    const int xcd = d & 7;
    const int l = d >> 3;
    const int rowBlk = xcd * 16 + (l >> 2);
    const int colBlk = l & 3;
    const long blockM = (long)rowBlk * 128;
    const long blockN = (long)colBlk * 128;

    floatx4 acc[4][4];
#pragma unroll
    for (int i = 0; i < 4; ++i)
#pragma unroll
        for (int j = 0; j < 4; ++j) acc[i][j] = (floatx4){0.f, 0.f, 0.f, 0.f};

    const int srow = tid >> 2;
    const int skoff = (tid & 3) * 8;
    const int ldsoff = srow * BK + skoff;
    const int fr = lane & 15;
    const int fq = (lane >> 4) * 8;

    for (int k0 = 0; k0 < KD; k0 += BK) {
        __syncthreads();
#pragma unroll
        for (int p = 0; p < 2; ++p) {
            const int row = srow + p * 64;
            const size_t aoff = (size_t)(blockM + row) * KD + k0 + skoff;
            const size_t boff = (size_t)(blockN + row) * KD + k0 + skoff;
            const int loff = ldsoff + p * 2048;
            __builtin_amdgcn_global_load_lds(
                (const __attribute__((address_space(1))) void*)(Ah + aoff),
                (__attribute__((address_space(3))) void*)(sAh + loff), 16, 0, 0);
            __builtin_amdgcn_global_load_lds(
                (const __attribute__((address_space(1))) void*)(Al + aoff),
                (__attribute__((address_space(3))) void*)(sAl + loff), 16, 0, 0);
            __builtin_amdgcn_global_load_lds(
                (const __attribute__((address_space(1))) void*)(BTh + boff),
                (__attribute__((address_space(3))) void*)(sBh + loff), 16, 0, 0);
            __builtin_amdgcn_global_load_lds(
                (const __attribute__((address_space(1))) void*)(BTl + boff),
                (__attribute__((address_space(3))) void*)(sBl + loff), 16, 0, 0);
        }
        __syncthreads();

        half8v fbh[4], fbl[4];
#pragma unroll
        for (int t = 0; t < 4; ++t) {
            fbh[t] = *(const half8v*)(sBh + (wn + t * 16 + fr) * BK + fq);
            fbl[t] = *(const half8v*)(sBl + (wn + t * 16 + fr) * BK + fq);
        }
#pragma unroll
        for (int i = 0; i < 4; ++i) {
            half8v fah = *(const half8v*)(sAh + (wm + i * 16 + fr) * BK + fq);
            half8v fal = *(const half8v*)(sAl + (wm + i * 16 + fr) * BK + fq);
#pragma unroll
            for (int j = 0; j < 4; ++j) {
                acc[i][j] = __builtin_amdgcn_mfma_f32_16x16x32_f16(fah, fbh[j], acc[i][j], 0, 0, 0);
                acc[i][j] = __builtin_amdgcn_mfma_f32_16x16x32_f16(fah, fbl[j], acc[i][j], 0, 0, 0);
                acc[i][j] = __builtin_amdgcn_mfma_f32_16x16x32_f16(fal, fbh[j], acc[i][j], 0, 0, 0);
            }
        }
    }

    // Epilogue: relu(h2) -> dot with w3 rows -> per-wave reduce -> atomicAdd.
    const int ocol = lane & 15;
    float p[E_];
#pragma unroll
    for (int e = 0; e < E_; ++e) p[e] = 0.0f;
#pragma unroll
    for (int j = 0; j < 4; ++j) {
        const int gn = (int)blockN + wn + j * 16 + ocol;   // h2 column in [0,512)
        const float bj = bias[gn];
        const float4 w3a = *(const float4*)(w3 + (size_t)gn * E_);
        const float4 w3b = *(const float4*)(w3 + (size_t)gn * E_ + 4);
        float colsum = 0.0f;
#pragma unroll
        for (int i = 0; i < 4; ++i)
#pragma unroll
            for (int r = 0; r < 4; ++r)
                colsum += fmaxf(acc[i][j][r] * OSCALE + bj, 0.0f);
        p[0] += colsum * w3a.x; p[1] += colsum * w3a.y;
        p[2] += colsum * w3a.z; p[3] += colsum * w3a.w;
        p[4] += colsum * w3b.x; p[5] += colsum * w3b.y;
        p[6] += colsum * w3b.z; p[7] += colsum * w3b.w;
    }
#pragma unroll
    for (int e = 0; e < E_; ++e)
#pragma unroll
        for (int off = 32; off > 0; off >>= 1)
            p[e] += __shfl_xor(p[e], off);
#pragma unroll
    for (int e = 0; e < E_; ++e)
        if (lane == e) atomicAdd(&cl_acc[rowBlk * E_ + e], p[e]);
}

// ---------------------------------------------------------------------------
// Finalize: cl = acc/128 + b3; argmax; hysteresis scan; stats; outputs.
// prev_expert_indices is dead in the reference (scan init zeros + is_first).
// ---------------------------------------------------------------------------
__global__ __launch_bounds__(128)
void finalize_kernel(const float* __restrict__ cl_acc, const float* __restrict__ b3,
                     float* __restrict__ out, int* __restrict__ experts_ws)
{
    __shared__ float cl[B_ * C_][E_];
    __shared__ int tops[B_ * C_];
    __shared__ int finals[B_ * C_];
    __shared__ int flips[B_];
    __shared__ float ent[B_ * C_];

    const int tid = threadIdx.x;  // 128 == B_*C_

    {
        int best = 0;
        float bvv = -1e30f;
#pragma unroll
        for (int e = 0; e < E_; ++e) {
            const float v = cl_acc[tid * E_ + e] * (1.0f / CHUNK_) + b3[e];
            cl[tid][e] = v;
            out[OUT_CL + tid * E_ + e] = v;
            if (v > bvv) { bvv = v; best = e; }   // first-max tiebreak == np.argmax
        }
        tops[tid] = best;
    }
    __syncthreads();

    if (tid < B_) {
        const int b = tid;
        int prev = 0, fl = 0;
        for (int c = 0; c < C_; ++c) {
            const int t = tops[b * C_ + c];
            int fin;
            if (c == 0) {
                fin = t;
            } else {
                const float cur = cl[b * C_ + c][t];
                const float pv = cl[b * C_ + c][prev];
                const bool sw = (cur - pv) > TAU_;
                if (sw) fl++;
                fin = sw ? t : prev;
            }
            finals[b * C_ + c] = fin;
            prev = fin;
        }
        flips[b] = fl;
    }

    {
        float m = cl[tid][0];
        for (int e = 1; e < E_; ++e) m = fmaxf(m, cl[tid][e]);
        float pr[E_], s = 0.0f;
        for (int e = 0; e < E_; ++e) { pr[e] = expf(cl[tid][e] - m); s += pr[e]; }
        const float inv = 1.0f / s;
        float h = 0.0f;
        for (int e = 0; e < E_; ++e) { const float pe = pr[e] * inv; h -= pe * logf(pe + 1e-8f); }
        ent[tid] = h;
    }
    __syncthreads();

    if (tid == 0) {
        float esum = 0.0f;
        for (int i = 0; i < B_ * C_; ++i) esum += ent[i];
        out[OUT_GE] = esum / (float)(B_ * C_);

        int cnt[E_];
        for (int e = 0; e < E_; ++e) cnt[e] = 0;
        for (int i = 0; i < B_ * C_; ++i) cnt[finals[i]]++;
        float n2 = 0.0f;
        for (int e = 0; e < E_; ++e) {
            const float u = (float)cnt[e] / (float)(B_ * C_);
            out[OUT_UT + e] = u;
            n2 += u * u;
        }
        const int totfl = flips[0] + flips[1] + flips[2] + flips[3];
        out[OUT_FR] = (float)totfl / (float)(B_ * (C_ - 1));
        out[OUT_RC] = sqrtf(n2);
    }

    out[OUT_EI + tid] = (float)finals[tid];
    experts_ws[tid] = finals[tid];
}

// ---------------------------------------------------------------------------
__global__ __launch_bounds__(256)
void routing_weights_kernel(const int* __restrict__ experts_ws, float* __restrict__ out)
{
    const int tok = blockIdx.x * 256 + threadIdx.x;
    const int b = tok >> 12;
    const int c = (tok & (S_ - 1)) >> 7;
    const int e = experts_ws[b * C_ + c];
    float4 v0 = make_float4(e == 0 ? 1.f : 0.f, e == 1 ? 1.f : 0.f,
                            e == 2 ? 1.f : 0.f, e == 3 ? 1.f : 0.f);
    float4 v1 = make_float4(e == 4 ? 1.f : 0.f, e == 5 ? 1.f : 0.f,
                            e == 6 ? 1.f : 0.f, e == 7 ? 1.f : 0.f);
    float4* dst = (float4*)(out + (size_t)tok * E_);
    dst[0] = v0;
    dst[1] = v1;
}

// ---------------------------------------------------------------------------
extern "C" void kernel_launch(void* const* d_in, const int* in_sizes, int n_in,
                              void* d_out, int out_size, void* d_ws, size_t ws_size,
                              hipStream_t stream)
{
    const float* x  = (const float*)d_in[0];
    const float* w1 = (const float*)d_in[2];
    const float* b1 = (const float*)d_in[3];
    const float* w2 = (const float*)d_in[4];
    const float* b2 = (const float*)d_in[5];
    const float* w3 = (const float*)d_in[6];
    const float* b3 = (const float*)d_in[7];
    float* out = (float*)d_out;

    half_t* xh   = (half_t*)d_ws;                    // 64 MB
    half_t* xl   = xh + (size_t)M_ * D_;             // 64 MB
    half_t* w1th = xl + (size_t)M_ * D_;             // 4 MB
    half_t* w1tl = w1th + (size_t)H_ * D_;           // 4 MB
    half_t* h1h  = w1tl + (size_t)H_ * D_;           // 32 MB
    half_t* h1l  = h1h + (size_t)M_ * H_;            // 32 MB
    half_t* w2th = h1l + (size_t)M_ * H_;            // 1 MB
    half_t* w2tl = w2th + (size_t)H2_ * H_;          // 1 MB
    float*  cl_acc = (float*)(w2tl + (size_t)H2_ * H_);  // 4 KB
    int* experts_ws = (int*)(cl_acc + B_ * C_ * E_);

    // zero the chunk-logit accumulator (ws is poisoned 0xAA before each call)
    hipMemsetAsync(cl_acc, 0, (size_t)B_ * C_ * E_ * sizeof(float), stream);

    convert_split_kernel<<<dim3((M_ * (D_ / 4)) / 256), dim3(256), 0, stream>>>(
        x, xh, xl, M_ * (D_ / 4));
    transpose_split_kernel<<<dim3(H_ / 32, D_ / 32), dim3(256), 0, stream>>>(w1, w1th, w1tl, D_, H_);
    transpose_split_kernel<<<dim3(H2_ / 32, H_ / 32), dim3(256), 0, stream>>>(w2, w2th, w2tl, H_, H2_);
    gemm1_kernel<<<dim3(H_ / 128, M_ / 128), dim3(256), 0, stream>>>(
        xh, xl, w1th, w1tl, b1, h1h, h1l);
    gemm2_fused_kernel<<<dim3(H2_ / 128, M_ / 128), dim3(256), 0, stream>>>(
        h1h, h1l, w2th, w2tl, b2, w3, cl_acc);
    finalize_kernel<<<dim3(1), dim3(128), 0, stream>>>(cl_acc, b3, out, experts_ws);
    routing_weights_kernel<<<dim3(M_ / 256), dim3(256), 0, stream>>>(experts_ws, out + OUT_RW);
}

// Round 4
// 424.881 us; speedup vs baseline: 2.7477x; 1.2158x over previous
//
#include <hip/hip_runtime.h>
#include <math.h>

typedef _Float16 half_t;
typedef __attribute__((ext_vector_type(4))) _Float16 half4v;
typedef __attribute__((ext_vector_type(8))) _Float16 half8v;
typedef __attribute__((ext_vector_type(4))) float floatx4;

constexpr int B_ = 4, S_ = 4096, D_ = 2048, H_ = 1024, H2_ = 512, E_ = 8;
constexpr int CHUNK_ = 128;
constexpr int C_ = S_ / CHUNK_;          // 32
constexpr int M_ = B_ * S_;              // 16384
constexpr float TAU_ = 0.7f;
// f16x2 scheme: A (activations) plain f16; W split hi+lo (pre-scaled x64 so
// residuals are f16-normal). Result = Ah*(Wh+Wl) = exact-W x rounded-A.
// A-rounding error is incoherent across a chunk's 128 tokens -> averages out
// in the chunk mean (~1e-5 final logit error). W stays ~fp32-exact.
constexpr float WSCALE = 64.0f, OSCALE = 1.0f / 64.0f;

constexpr int OUT_RW = 0;
constexpr int OUT_EI = OUT_RW + B_ * S_ * E_;
constexpr int OUT_CL = OUT_EI + B_ * C_;
constexpr int OUT_GE = OUT_CL + B_ * C_ * E_;
constexpr int OUT_UT = OUT_GE + 1;
constexpr int OUT_FR = OUT_UT + E_;
constexpr int OUT_RC = OUT_FR + 1;

// ---------------------------------------------------------------------------
// fp32 -> f16 (plain round-to-nearest), float4 loads.
// ---------------------------------------------------------------------------
__global__ __launch_bounds__(256)
void convert_f16_kernel(const float* __restrict__ src, half_t* __restrict__ dst, int n4)
{
    const int i = blockIdx.x * 256 + threadIdx.x;
    if (i >= n4) return;
    const float4 v = ((const float4*)src)[i];
    half4v h;
    h.x = (half_t)v.x; h.y = (half_t)v.y; h.z = (half_t)v.z; h.w = (half_t)v.w;
    ((half4v*)dst)[i] = h;
}

// ---------------------------------------------------------------------------
// Transpose W [K,N] fp32 -> WT hi/lo f16 [N,K], pre-scaled x64.
// ---------------------------------------------------------------------------
__global__ __launch_bounds__(256)
void transpose_split_kernel(const float* __restrict__ W, half_t* __restrict__ hi,
                            half_t* __restrict__ lo, int K, int N)
{
    __shared__ float tile[32][33];
    const int tx = threadIdx.x & 31;
    const int ty = threadIdx.x >> 5;
    const int k0 = blockIdx.y * 32;
    const int n0 = blockIdx.x * 32;
#pragma unroll
    for (int r = 0; r < 4; ++r)
        tile[ty + r * 8][tx] = W[(size_t)(k0 + ty + r * 8) * N + n0 + tx];
    __syncthreads();
#pragma unroll
    for (int r = 0; r < 4; ++r) {
        const float v = tile[tx][ty + r * 8] * WSCALE;
        const half_t h = (half_t)v;
        const size_t off = (size_t)(n0 + ty + r * 8) * K + k0 + tx;
        hi[off] = h;
        lo[off] = (half_t)(v - (float)h);
    }
}

// ---------------------------------------------------------------------------
// GEMM1: h1 = relu(x @ w1 + b1) -> f16. f16x2 (2 MFMA/tile), 128x128 tile,
// BK=32, global_load_lds(16B), XCD-swizzled, 24 KB LDS.
// ---------------------------------------------------------------------------
__global__ __launch_bounds__(256, 3)
void gemm1_kernel(const half_t* __restrict__ Ah,
                  const half_t* __restrict__ BTh, const half_t* __restrict__ BTl,
                  const float* __restrict__ bias, half_t* __restrict__ outh)
{
    constexpr int KD = D_, ND = H_, BK = 32;
    __shared__ __align__(16) half_t sAh[128 * BK];
    __shared__ __align__(16) half_t sBh[128 * BK];
    __shared__ __align__(16) half_t sBl[128 * BK];

    const int tid = threadIdx.x;
    const int lane = tid & 63;
    const int wave = tid >> 6;
    const int wm = (wave & 1) * 64;
    const int wn = (wave >> 1) * 64;
    // XCD swizzle: dispatch d=y*8+x -> xcd=x; each XCD owns an M-stripe.
    const int rowBlk = blockIdx.x * 16 + (blockIdx.y >> 3);
    const int colBlk = blockIdx.y & 7;
    const long blockM = (long)rowBlk * 128;
    const long blockN = (long)colBlk * 128;

    floatx4 acc[4][4];
#pragma unroll
    for (int i = 0; i < 4; ++i)
#pragma unroll
        for (int j = 0; j < 4; ++j) acc[i][j] = (floatx4){0.f, 0.f, 0.f, 0.f};

    const int srow = tid >> 2;
    const int skoff = (tid & 3) * 8;
    const int ldsoff = srow * BK + skoff;
    const int fr = lane & 15;
    const int fq = (lane >> 4) * 8;

    for (int k0 = 0; k0 < KD; k0 += BK) {
        __syncthreads();
#pragma unroll
        for (int p = 0; p < 2; ++p) {
            const int row = srow + p * 64;
            const size_t aoff = (size_t)(blockM + row) * KD + k0 + skoff;
            const size_t boff = (size_t)(blockN + row) * KD + k0 + skoff;
            const int loff = ldsoff + p * 2048;
            __builtin_amdgcn_global_load_lds(
                (const __attribute__((address_space(1))) void*)(Ah + aoff),
                (__attribute__((address_space(3))) void*)(sAh + loff), 16, 0, 0);
            __builtin_amdgcn_global_load_lds(
                (const __attribute__((address_space(1))) void*)(BTh + boff),
                (__attribute__((address_space(3))) void*)(sBh + loff), 16, 0, 0);
            __builtin_amdgcn_global_load_lds(
                (const __attribute__((address_space(1))) void*)(BTl + boff),
                (__attribute__((address_space(3))) void*)(sBl + loff), 16, 0, 0);
        }
        __syncthreads();

        half8v fbh[4], fbl[4];
#pragma unroll
        for (int t = 0; t < 4; ++t) {
            fbh[t] = *(const half8v*)(sBh + (wn + t * 16 + fr) * BK + fq);
            fbl[t] = *(const half8v*)(sBl + (wn + t * 16 + fr) * BK + fq);
        }
#pragma unroll
        for (int i = 0; i < 4; ++i) {
            half8v fah = *(const half8v*)(sAh + (wm + i * 16 + fr) * BK + fq);
#pragma unroll
            for (int j = 0; j < 4; ++j) {
                acc[i][j] = __builtin_amdgcn_mfma_f32_16x16x32_f16(fah, fbh[j], acc[i][j], 0, 0, 0);
                acc[i][j] = __builtin_amdgcn_mfma_f32_16x16x32_f16(fah, fbl[j], acc[i][j], 0, 0, 0);
            }
        }
    }

    const int orow = (lane >> 4) * 4;
    const int ocol = lane & 15;
#pragma unroll
    for (int j = 0; j < 4; ++j) {
        const long gn = blockN + wn + j * 16 + ocol;
        const float bj = bias[gn];
#pragma unroll
        for (int i = 0; i < 4; ++i) {
#pragma unroll
            for (int r = 0; r < 4; ++r) {
                const float v = fmaxf(acc[i][j][r] * OSCALE + bj, 0.0f);
                const size_t off = (size_t)(blockM + wm + i * 16 + orow + r) * ND + gn;
                outh[off] = (half_t)v;
            }
        }
    }
}

// ---------------------------------------------------------------------------
// GEMM2 fused: relu(h1 @ w2 + b2) @ w3, chunk-summed into cl_acc via
// device-scope atomics. h2 never materialized. f16x2.
// ---------------------------------------------------------------------------
__global__ __launch_bounds__(256, 3)
void gemm2_fused_kernel(const half_t* __restrict__ Ah,
                        const half_t* __restrict__ BTh, const half_t* __restrict__ BTl,
                        const float* __restrict__ bias, const float* __restrict__ w3,
                        float* __restrict__ cl_acc)
{
    constexpr int KD = H_, BK = 32;
    __shared__ __align__(16) half_t sAh[128 * BK];
    __shared__ __align__(16) half_t sBh[128 * BK];
    __shared__ __align__(16) half_t sBl[128 * BK];

    const int tid = threadIdx.x;
    const int lane = tid & 63;
    const int wave = tid >> 6;
    const int wm = (wave & 1) * 64;
    const int wn = (wave >> 1) * 64;
    const int d = blockIdx.y * 4 + blockIdx.x;
    const int xcd = d & 7;
    const int l = d >> 3;
    const int rowBlk = xcd * 16 + (l >> 2);
    const int colBlk = l & 3;
    const long blockM = (long)rowBlk * 128;
    const long blockN = (long)colBlk * 128;

    floatx4 acc[4][4];
#pragma unroll
    for (int i = 0; i < 4; ++i)
#pragma unroll
        for (int j = 0; j < 4; ++j) acc[i][j] = (floatx4){0.f, 0.f, 0.f, 0.f};

    const int srow = tid >> 2;
    const int skoff = (tid & 3) * 8;
    const int ldsoff = srow * BK + skoff;
    const int fr = lane & 15;
    const int fq = (lane >> 4) * 8;

    for (int k0 = 0; k0 < KD; k0 += BK) {
        __syncthreads();
#pragma unroll
        for (int p = 0; p < 2; ++p) {
            const int row = srow + p * 64;
            const size_t aoff = (size_t)(blockM + row) * KD + k0 + skoff;
            const size_t boff = (size_t)(blockN + row) * KD + k0 + skoff;
            const int loff = ldsoff + p * 2048;
            __builtin_amdgcn_global_load_lds(
                (const __attribute__((address_space(1))) void*)(Ah + aoff),
                (__attribute__((address_space(3))) void*)(sAh + loff), 16, 0, 0);
            __builtin_amdgcn_global_load_lds(
                (const __attribute__((address_space(1))) void*)(BTh + boff),
                (__attribute__((address_space(3))) void*)(sBh + loff), 16, 0, 0);
            __builtin_amdgcn_global_load_lds(
                (const __attribute__((address_space(1))) void*)(BTl + boff),
                (__attribute__((address_space(3))) void*)(sBl + loff), 16, 0, 0);
        }
        __syncthreads();

        half8v fbh[4], fbl[4];
#pragma unroll
        for (int t = 0; t < 4; ++t) {
            fbh[t] = *(const half8v*)(sBh + (wn + t * 16 + fr) * BK + fq);
            fbl[t] = *(const half8v*)(sBl + (wn + t * 16 + fr) * BK + fq);
        }
#pragma unroll
        for (int i = 0; i < 4; ++i) {
            half8v fah = *(const half8v*)(sAh + (wm + i * 16 + fr) * BK + fq);
#pragma unroll
            for (int j = 0; j < 4; ++j) {
                acc[i][j] = __builtin_amdgcn_mfma_f32_16x16x32_f16(fah, fbh[j], acc[i][j], 0, 0, 0);
                acc[i][j] = __builtin_amdgcn_mfma_f32_16x16x32_f16(fah, fbl[j], acc[i][j], 0, 0, 0);
            }
        }
    }

    // Epilogue: relu(h2) -> dot w3 rows -> wave reduce -> atomicAdd per chunk.
    const int ocol = lane & 15;
    float p[E_];
#pragma unroll
    for (int e = 0; e < E_; ++e) p[e] = 0.0f;
#pragma unroll
    for (int j = 0; j < 4; ++j) {
        const int gn = (int)blockN + wn + j * 16 + ocol;
        const float bj = bias[gn];
        const float4 w3a = *(const float4*)(w3 + (size_t)gn * E_);
        const float4 w3b = *(const float4*)(w3 + (size_t)gn * E_ + 4);
        float colsum = 0.0f;
#pragma unroll
        for (int i = 0; i < 4; ++i)
#pragma unroll
            for (int r = 0; r < 4; ++r)
                colsum += fmaxf(acc[i][j][r] * OSCALE + bj, 0.0f);
        p[0] += colsum * w3a.x; p[1] += colsum * w3a.y;
        p[2] += colsum * w3a.z; p[3] += colsum * w3a.w;
        p[4] += colsum * w3b.x; p[5] += colsum * w3b.y;
        p[6] += colsum * w3b.z; p[7] += colsum * w3b.w;
    }
#pragma unroll
    for (int e = 0; e < E_; ++e)
#pragma unroll
        for (int off = 32; off > 0; off >>= 1)
            p[e] += __shfl_xor(p[e], off);
#pragma unroll
    for (int e = 0; e < E_; ++e)
        if (lane == e) atomicAdd(&cl_acc[rowBlk * E_ + e], p[e]);
}

// ---------------------------------------------------------------------------
// Finalize: cl = acc/128 + b3; argmax; hysteresis scan; stats.
// prev_expert_indices is dead in the reference (scan init zeros + is_first).
// ---------------------------------------------------------------------------
__global__ __launch_bounds__(128)
void finalize_kernel(const float* __restrict__ cl_acc, const float* __restrict__ b3,
                     float* __restrict__ out, int* __restrict__ experts_ws)
{
    __shared__ float cl[B_ * C_][E_];
    __shared__ int tops[B_ * C_];
    __shared__ int finals[B_ * C_];
    __shared__ int flips[B_];
    __shared__ float ent[B_ * C_];

    const int tid = threadIdx.x;  // 128 == B_*C_

    {
        int best = 0;
        float bvv = -1e30f;
#pragma unroll
        for (int e = 0; e < E_; ++e) {
            const float v = cl_acc[tid * E_ + e] * (1.0f / CHUNK_) + b3[e];
            cl[tid][e] = v;
            out[OUT_CL + tid * E_ + e] = v;
            if (v > bvv) { bvv = v; best = e; }
        }
        tops[tid] = best;
    }
    __syncthreads();

    if (tid < B_) {
        const int b = tid;
        int prev = 0, fl = 0;
        for (int c = 0; c < C_; ++c) {
            const int t = tops[b * C_ + c];
            int fin;
            if (c == 0) {
                fin = t;
            } else {
                const float cur = cl[b * C_ + c][t];
                const float pv = cl[b * C_ + c][prev];
                const bool sw = (cur - pv) > TAU_;
                if (sw) fl++;
                fin = sw ? t : prev;
            }
            finals[b * C_ + c] = fin;
            prev = fin;
        }
        flips[b] = fl;
    }

    {
        float m = cl[tid][0];
        for (int e = 1; e < E_; ++e) m = fmaxf(m, cl[tid][e]);
        float pr[E_], s = 0.0f;
        for (int e = 0; e < E_; ++e) { pr[e] = expf(cl[tid][e] - m); s += pr[e]; }
        const float inv = 1.0f / s;
        float h = 0.0f;
        for (int e = 0; e < E_; ++e) { const float pe = pr[e] * inv; h -= pe * logf(pe + 1e-8f); }
        ent[tid] = h;
    }
    __syncthreads();

    if (tid == 0) {
        float esum = 0.0f;
        for (int i = 0; i < B_ * C_; ++i) esum += ent[i];
        out[OUT_GE] = esum / (float)(B_ * C_);

        int cnt[E_];
        for (int e = 0; e < E_; ++e) cnt[e] = 0;
        for (int i = 0; i < B_ * C_; ++i) cnt[finals[i]]++;
        float n2 = 0.0f;
        for (int e = 0; e < E_; ++e) {
            const float u = (float)cnt[e] / (float)(B_ * C_);
            out[OUT_UT + e] = u;
            n2 += u * u;
        }
        const int totfl = flips[0] + flips[1] + flips[2] + flips[3];
        out[OUT_FR] = (float)totfl / (float)(B_ * (C_ - 1));
        out[OUT_RC] = sqrtf(n2);
    }

    out[OUT_EI + tid] = (float)finals[tid];
    experts_ws[tid] = finals[tid];
}

// ---------------------------------------------------------------------------
__global__ __launch_bounds__(256)
void routing_weights_kernel(const int* __restrict__ experts_ws, float* __restrict__ out)
{
    const int tok = blockIdx.x * 256 + threadIdx.x;
    const int b = tok >> 12;
    const int c = (tok & (S_ - 1)) >> 7;
    const int e = experts_ws[b * C_ + c];
    float4 v0 = make_float4(e == 0 ? 1.f : 0.f, e == 1 ? 1.f : 0.f,
                            e == 2 ? 1.f : 0.f, e == 3 ? 1.f : 0.f);
    float4 v1 = make_float4(e == 4 ? 1.f : 0.f, e == 5 ? 1.f : 0.f,
                            e == 6 ? 1.f : 0.f, e == 7 ? 1.f : 0.f);
    float4* dst = (float4*)(out + (size_t)tok * E_);
    dst[0] = v0;
    dst[1] = v1;
}

// ---------------------------------------------------------------------------
extern "C" void kernel_launch(void* const* d_in, const int* in_sizes, int n_in,
                              void* d_out, int out_size, void* d_ws, size_t ws_size,
                              hipStream_t stream)
{
    const float* x  = (const float*)d_in[0];
    const float* w1 = (const float*)d_in[2];
    const float* b1 = (const float*)d_in[3];
    const float* w2 = (const float*)d_in[4];
    const float* b2 = (const float*)d_in[5];
    const float* w3 = (const float*)d_in[6];
    const float* b3 = (const float*)d_in[7];
    float* out = (float*)d_out;

    half_t* xh   = (half_t*)d_ws;                    // 64 MB
    half_t* w1th = xh + (size_t)M_ * D_;             // 4 MB
    half_t* w1tl = w1th + (size_t)H_ * D_;           // 4 MB
    half_t* h1h  = w1tl + (size_t)H_ * D_;           // 32 MB
    half_t* w2th = h1h + (size_t)M_ * H_;            // 1 MB
    half_t* w2tl = w2th + (size_t)H2_ * H_;          // 1 MB
    float*  cl_acc = (float*)(w2tl + (size_t)H2_ * H_);  // 4 KB
    int* experts_ws = (int*)(cl_acc + B_ * C_ * E_);

    hipMemsetAsync(cl_acc, 0, (size_t)B_ * C_ * E_ * sizeof(float), stream);

    convert_f16_kernel<<<dim3((M_ * (D_ / 4)) / 256), dim3(256), 0, stream>>>(
        x, xh, M_ * (D_ / 4));
    transpose_split_kernel<<<dim3(H_ / 32, D_ / 32), dim3(256), 0, stream>>>(w1, w1th, w1tl, D_, H_);
    transpose_split_kernel<<<dim3(H2_ / 32, H_ / 32), dim3(256), 0, stream>>>(w2, w2th, w2tl, H_, H2_);
    gemm1_kernel<<<dim3(H_ / 128, M_ / 128), dim3(256), 0, stream>>>(
        xh, w1th, w1tl, b1, h1h);
    gemm2_fused_kernel<<<dim3(H2_ / 128, M_ / 128), dim3(256), 0, stream>>>(
        h1h, w2th, w2tl, b2, w3, cl_acc);
    finalize_kernel<<<dim3(1), dim3(128), 0, stream>>>(cl_acc, b3, out, experts_ws);
    routing_weights_kernel<<<dim3(M_ / 256), dim3(256), 0, stream>>>(experts_ws, out + OUT_RW);
}

// Round 5
// 367.236 us; speedup vs baseline: 3.1790x; 1.1570x over previous
//
#include <hip/hip_runtime.h>
#include <math.h>

typedef _Float16 half_t;
typedef __attribute__((ext_vector_type(4))) _Float16 half4v;
typedef __attribute__((ext_vector_type(8))) _Float16 half8v;
typedef __attribute__((ext_vector_type(4))) float floatx4;

constexpr int B_ = 4, S_ = 4096, D_ = 2048, H_ = 1024, H2_ = 512, E_ = 8;
constexpr int CHUNK_ = 128;
constexpr int C_ = S_ / CHUNK_;          // 32
constexpr int M_ = B_ * S_;              // 16384
constexpr float TAU_ = 0.7f;
// Precision ledger (measured R2 absmax=0 full-split; R4 absmax=2e-3 after
// dropping A-split):
//  - A-rounding + W1-rounding: token-incoherent -> chunk-mean averages ~sqrt(128)
//    -> GEMM1 runs PURE f16 (1 MFMA/tile).
//  - W2-rounding: enters via h1>=0 (positive mean) -> coherent across tokens,
//    chunk-mean does NOT reduce -> keep W2 split (f16x2), pre-scaled x64.
constexpr float WSCALE = 64.0f, OSCALE = 1.0f / 64.0f;

constexpr int OUT_RW = 0;
constexpr int OUT_EI = OUT_RW + B_ * S_ * E_;
constexpr int OUT_CL = OUT_EI + B_ * C_;
constexpr int OUT_GE = OUT_CL + B_ * C_ * E_;
constexpr int OUT_UT = OUT_GE + 1;
constexpr int OUT_FR = OUT_UT + E_;
constexpr int OUT_RC = OUT_FR + 1;

// ---------------------------------------------------------------------------
// Transpose W [K,N] fp32 -> WT f16 [N,K], plain (for w1).
// ---------------------------------------------------------------------------
__global__ __launch_bounds__(256)
void transpose_f16_kernel(const float* __restrict__ W, half_t* __restrict__ outT,
                          int K, int N)
{
    __shared__ float tile[32][33];
    const int tx = threadIdx.x & 31;
    const int ty = threadIdx.x >> 5;
    const int k0 = blockIdx.y * 32;
    const int n0 = blockIdx.x * 32;
#pragma unroll
    for (int r = 0; r < 4; ++r)
        tile[ty + r * 8][tx] = W[(size_t)(k0 + ty + r * 8) * N + n0 + tx];
    __syncthreads();
#pragma unroll
    for (int r = 0; r < 4; ++r)
        outT[(size_t)(n0 + ty + r * 8) * K + k0 + tx] = (half_t)tile[tx][ty + r * 8];
}

// ---------------------------------------------------------------------------
// Transpose W [K,N] fp32 -> WT hi/lo f16 [N,K], pre-scaled x64 (for w2).
// ---------------------------------------------------------------------------
__global__ __launch_bounds__(256)
void transpose_split_kernel(const float* __restrict__ W, half_t* __restrict__ hi,
                            half_t* __restrict__ lo, int K, int N)
{
    __shared__ float tile[32][33];
    const int tx = threadIdx.x & 31;
    const int ty = threadIdx.x >> 5;
    const int k0 = blockIdx.y * 32;
    const int n0 = blockIdx.x * 32;
#pragma unroll
    for (int r = 0; r < 4; ++r)
        tile[ty + r * 8][tx] = W[(size_t)(k0 + ty + r * 8) * N + n0 + tx];
    __syncthreads();
#pragma unroll
    for (int r = 0; r < 4; ++r) {
        const float v = tile[tx][ty + r * 8] * WSCALE;
        const half_t h = (half_t)v;
        const size_t off = (size_t)(n0 + ty + r * 8) * K + k0 + tx;
        hi[off] = h;
        lo[off] = (half_t)(v - (float)h);
    }
}

// ---------------------------------------------------------------------------
// GEMM1: h1 = relu(x @ w1 + b1) -> f16, pure f16 MFMA (16 MFMA/k-iter, m97
// shape). A staged fp32->f16 IN-KERNEL (global->VGPR->cvt->ds_write_b128);
// B via global_load_lds(16B). 128x128 tile, BK=32, 16 KB LDS, XCD-swizzled.
// ---------------------------------------------------------------------------
__global__ __launch_bounds__(256, 3)
void gemm1_kernel(const float* __restrict__ X,
                  const half_t* __restrict__ BTh,
                  const float* __restrict__ bias, half_t* __restrict__ outh)
{
    constexpr int KD = D_, ND = H_, BK = 32;
    __shared__ __align__(16) half_t sA[128 * BK];
    __shared__ __align__(16) half_t sB[128 * BK];

    const int tid = threadIdx.x;
    const int lane = tid & 63;
    const int wave = tid >> 6;
    const int wm = (wave & 1) * 64;
    const int wn = (wave >> 1) * 64;
    // XCD swizzle: d=by*8+bx -> xcd=bx owns a 16-rowBlk M-stripe; 8 consecutive
    // by share one A row-block (1 MB fp32 reused 8x in L2).
    const int rowBlk = blockIdx.x * 16 + (blockIdx.y >> 3);
    const int colBlk = blockIdx.y & 7;
    const long blockM = (long)rowBlk * 128;
    const long blockN = (long)colBlk * 128;

    floatx4 acc[4][4];
#pragma unroll
    for (int i = 0; i < 4; ++i)
#pragma unroll
        for (int j = 0; j < 4; ++j) acc[i][j] = (floatx4){0.f, 0.f, 0.f, 0.f};

    const int srow = tid >> 2;            // 0..63
    const int skoff = (tid & 3) * 8;      // f16/float element offset in K-tile
    const int ldsoff = srow * BK + skoff;
    const int fr = lane & 15;
    const int fq = (lane >> 4) * 8;

    const float* Xrow0 = X + (size_t)(blockM + srow) * KD + skoff;
    const float* Xrow1 = Xrow0 + (size_t)64 * KD;

    for (int k0 = 0; k0 < KD; k0 += BK) {
        // A: fp32 VGPR loads (issue before barrier — no LDS hazard)
        const float4 a00 = *(const float4*)(Xrow0 + k0);
        const float4 a01 = *(const float4*)(Xrow0 + k0 + 4);
        const float4 a10 = *(const float4*)(Xrow1 + k0);
        const float4 a11 = *(const float4*)(Xrow1 + k0 + 4);
        __syncthreads();                 // prev iter's LDS reads complete
        // B: direct global->LDS
#pragma unroll
        for (int p = 0; p < 2; ++p) {
            const size_t boff = (size_t)(blockN + srow + p * 64) * KD + k0 + skoff;
            __builtin_amdgcn_global_load_lds(
                (const __attribute__((address_space(1))) void*)(BTh + boff),
                (__attribute__((address_space(3))) void*)(sB + ldsoff + p * 2048), 16, 0, 0);
        }
        // A: convert + LDS store (RNE via scalar cvt)
        half8v h0, h1v;
        h0.s0 = (half_t)a00.x; h0.s1 = (half_t)a00.y; h0.s2 = (half_t)a00.z; h0.s3 = (half_t)a00.w;
        h0.s4 = (half_t)a01.x; h0.s5 = (half_t)a01.y; h0.s6 = (half_t)a01.z; h0.s7 = (half_t)a01.w;
        h1v.s0 = (half_t)a10.x; h1v.s1 = (half_t)a10.y; h1v.s2 = (half_t)a10.z; h1v.s3 = (half_t)a10.w;
        h1v.s4 = (half_t)a11.x; h1v.s5 = (half_t)a11.y; h1v.s6 = (half_t)a11.z; h1v.s7 = (half_t)a11.w;
        *(half8v*)(sA + ldsoff) = h0;
        *(half8v*)(sA + ldsoff + 2048) = h1v;
        __syncthreads();

        half8v fb[4];
#pragma unroll
        for (int t = 0; t < 4; ++t)
            fb[t] = *(const half8v*)(sB + (wn + t * 16 + fr) * BK + fq);
#pragma unroll
        for (int i = 0; i < 4; ++i) {
            const half8v fa = *(const half8v*)(sA + (wm + i * 16 + fr) * BK + fq);
#pragma unroll
            for (int j = 0; j < 4; ++j)
                acc[i][j] = __builtin_amdgcn_mfma_f32_16x16x32_f16(fa, fb[j], acc[i][j], 0, 0, 0);
        }
    }

    const int orow = (lane >> 4) * 4;
    const int ocol = lane & 15;
#pragma unroll
    for (int j = 0; j < 4; ++j) {
        const long gn = blockN + wn + j * 16 + ocol;
        const float bj = bias[gn];
#pragma unroll
        for (int i = 0; i < 4; ++i) {
#pragma unroll
            for (int r = 0; r < 4; ++r) {
                const float v = fmaxf(acc[i][j][r] + bj, 0.0f);  // no OSCALE: w1 unscaled
                const size_t off = (size_t)(blockM + wm + i * 16 + orow + r) * ND + gn;
                outh[off] = (half_t)v;
            }
        }
    }
}

// ---------------------------------------------------------------------------
// GEMM2 fused: relu(h1 @ w2 + b2) @ w3, chunk-summed into cl_acc via
// device-scope atomics. h2 never materialized. f16x2 (W2 split kept).
// ---------------------------------------------------------------------------
__global__ __launch_bounds__(256, 3)
void gemm2_fused_kernel(const half_t* __restrict__ Ah,
                        const half_t* __restrict__ BTh, const half_t* __restrict__ BTl,
                        const float* __restrict__ bias, const float* __restrict__ w3,
                        float* __restrict__ cl_acc)
{
    constexpr int KD = H_, BK = 32;
    __shared__ __align__(16) half_t sAh[128 * BK];
    __shared__ __align__(16) half_t sBh[128 * BK];
    __shared__ __align__(16) half_t sBl[128 * BK];

    const int tid = threadIdx.x;
    const int lane = tid & 63;
    const int wave = tid >> 6;
    const int wm = (wave & 1) * 64;
    const int wn = (wave >> 1) * 64;
    const int d = blockIdx.y * 4 + blockIdx.x;
    const int xcd = d & 7;
    const int l = d >> 3;
    const int rowBlk = xcd * 16 + (l >> 2);
    const int colBlk = l & 3;
    const long blockM = (long)rowBlk * 128;
    const long blockN = (long)colBlk * 128;

    floatx4 acc[4][4];
#pragma unroll
    for (int i = 0; i < 4; ++i)
#pragma unroll
        for (int j = 0; j < 4; ++j) acc[i][j] = (floatx4){0.f, 0.f, 0.f, 0.f};

    const int srow = tid >> 2;
    const int skoff = (tid & 3) * 8;
    const int ldsoff = srow * BK + skoff;
    const int fr = lane & 15;
    const int fq = (lane >> 4) * 8;

    for (int k0 = 0; k0 < KD; k0 += BK) {
        __syncthreads();
#pragma unroll
        for (int p = 0; p < 2; ++p) {
            const int row = srow + p * 64;
            const size_t aoff = (size_t)(blockM + row) * KD + k0 + skoff;
            const size_t boff = (size_t)(blockN + row) * KD + k0 + skoff;
            const int loff = ldsoff + p * 2048;
            __builtin_amdgcn_global_load_lds(
                (const __attribute__((address_space(1))) void*)(Ah + aoff),
                (__attribute__((address_space(3))) void*)(sAh + loff), 16, 0, 0);
            __builtin_amdgcn_global_load_lds(
                (const __attribute__((address_space(1))) void*)(BTh + boff),
                (__attribute__((address_space(3))) void*)(sBh + loff), 16, 0, 0);
            __builtin_amdgcn_global_load_lds(
                (const __attribute__((address_space(1))) void*)(BTl + boff),
                (__attribute__((address_space(3))) void*)(sBl + loff), 16, 0, 0);
        }
        __syncthreads();

        half8v fbh[4], fbl[4];
#pragma unroll
        for (int t = 0; t < 4; ++t) {
            fbh[t] = *(const half8v*)(sBh + (wn + t * 16 + fr) * BK + fq);
            fbl[t] = *(const half8v*)(sBl + (wn + t * 16 + fr) * BK + fq);
        }
#pragma unroll
        for (int i = 0; i < 4; ++i) {
            const half8v fah = *(const half8v*)(sAh + (wm + i * 16 + fr) * BK + fq);
#pragma unroll
            for (int j = 0; j < 4; ++j) {
                acc[i][j] = __builtin_amdgcn_mfma_f32_16x16x32_f16(fah, fbh[j], acc[i][j], 0, 0, 0);
                acc[i][j] = __builtin_amdgcn_mfma_f32_16x16x32_f16(fah, fbl[j], acc[i][j], 0, 0, 0);
            }
        }
    }

    const int ocol = lane & 15;
    float p[E_];
#pragma unroll
    for (int e = 0; e < E_; ++e) p[e] = 0.0f;
#pragma unroll
    for (int j = 0; j < 4; ++j) {
        const int gn = (int)blockN + wn + j * 16 + ocol;
        const float bj = bias[gn];
        const float4 w3a = *(const float4*)(w3 + (size_t)gn * E_);
        const float4 w3b = *(const float4*)(w3 + (size_t)gn * E_ + 4);
        float colsum = 0.0f;
#pragma unroll
        for (int i = 0; i < 4; ++i)
#pragma unroll
            for (int r = 0; r < 4; ++r)
                colsum += fmaxf(acc[i][j][r] * OSCALE + bj, 0.0f);
        p[0] += colsum * w3a.x; p[1] += colsum * w3a.y;
        p[2] += colsum * w3a.z; p[3] += colsum * w3a.w;
        p[4] += colsum * w3b.x; p[5] += colsum * w3b.y;
        p[6] += colsum * w3b.z; p[7] += colsum * w3b.w;
    }
#pragma unroll
    for (int e = 0; e < E_; ++e)
#pragma unroll
        for (int off = 32; off > 0; off >>= 1)
            p[e] += __shfl_xor(p[e], off);
#pragma unroll
    for (int e = 0; e < E_; ++e)
        if (lane == e) atomicAdd(&cl_acc[rowBlk * E_ + e], p[e]);
}

// ---------------------------------------------------------------------------
// Finalize: cl = acc/128 + b3; argmax; hysteresis scan; stats.
// prev_expert_indices is dead in the reference (scan init zeros + is_first).
// ---------------------------------------------------------------------------
__global__ __launch_bounds__(128)
void finalize_kernel(const float* __restrict__ cl_acc, const float* __restrict__ b3,
                     float* __restrict__ out, int* __restrict__ experts_ws)
{
    __shared__ float cl[B_ * C_][E_];
    __shared__ int tops[B_ * C_];
    __shared__ int finals[B_ * C_];
    __shared__ int flips[B_];
    __shared__ float ent[B_ * C_];

    const int tid = threadIdx.x;  // 128 == B_*C_

    {
        int best = 0;
        float bvv = -1e30f;
#pragma unroll
        for (int e = 0; e < E_; ++e) {
            const float v = cl_acc[tid * E_ + e] * (1.0f / CHUNK_) + b3[e];
            cl[tid][e] = v;
            out[OUT_CL + tid * E_ + e] = v;
            if (v > bvv) { bvv = v; best = e; }
        }
        tops[tid] = best;
    }
    __syncthreads();

    if (tid < B_) {
        const int b = tid;
        int prev = 0, fl = 0;
        for (int c = 0; c < C_; ++c) {
            const int t = tops[b * C_ + c];
            int fin;
            if (c == 0) {
                fin = t;
            } else {
                const float cur = cl[b * C_ + c][t];
                const float pv = cl[b * C_ + c][prev];
                const bool sw = (cur - pv) > TAU_;
                if (sw) fl++;
                fin = sw ? t : prev;
            }
            finals[b * C_ + c] = fin;
            prev = fin;
        }
        flips[b] = fl;
    }

    {
        float m = cl[tid][0];
        for (int e = 1; e < E_; ++e) m = fmaxf(m, cl[tid][e]);
        float pr[E_], s = 0.0f;
        for (int e = 0; e < E_; ++e) { pr[e] = expf(cl[tid][e] - m); s += pr[e]; }
        const float inv = 1.0f / s;
        float h = 0.0f;
        for (int e = 0; e < E_; ++e) { const float pe = pr[e] * inv; h -= pe * logf(pe + 1e-8f); }
        ent[tid] = h;
    }
    __syncthreads();

    if (tid == 0) {
        float esum = 0.0f;
        for (int i = 0; i < B_ * C_; ++i) esum += ent[i];
        out[OUT_GE] = esum / (float)(B_ * C_);

        int cnt[E_];
        for (int e = 0; e < E_; ++e) cnt[e] = 0;
        for (int i = 0; i < B_ * C_; ++i) cnt[finals[i]]++;
        float n2 = 0.0f;
        for (int e = 0; e < E_; ++e) {
            const float u = (float)cnt[e] / (float)(B_ * C_);
            out[OUT_UT + e] = u;
            n2 += u * u;
        }
        const int totfl = flips[0] + flips[1] + flips[2] + flips[3];
        out[OUT_FR] = (float)totfl / (float)(B_ * (C_ - 1));
        out[OUT_RC] = sqrtf(n2);
    }

    out[OUT_EI + tid] = (float)finals[tid];
    experts_ws[tid] = finals[tid];
}

// ---------------------------------------------------------------------------
__global__ __launch_bounds__(256)
void routing_weights_kernel(const int* __restrict__ experts_ws, float* __restrict__ out)
{
    const int tok = blockIdx.x * 256 + threadIdx.x;
    const int b = tok >> 12;
    const int c = (tok & (S_ - 1)) >> 7;
    const int e = experts_ws[b * C_ + c];
    float4 v0 = make_float4(e == 0 ? 1.f : 0.f, e == 1 ? 1.f : 0.f,
                            e == 2 ? 1.f : 0.f, e == 3 ? 1.f : 0.f);
    float4 v1 = make_float4(e == 4 ? 1.f : 0.f, e == 5 ? 1.f : 0.f,
                            e == 6 ? 1.f : 0.f, e == 7 ? 1.f : 0.f);
    float4* dst = (float4*)(out + (size_t)tok * E_);
    dst[0] = v0;
    dst[1] = v1;
}

// ---------------------------------------------------------------------------
extern "C" void kernel_launch(void* const* d_in, const int* in_sizes, int n_in,
                              void* d_out, int out_size, void* d_ws, size_t ws_size,
                              hipStream_t stream)
{
    const float* x  = (const float*)d_in[0];
    const float* w1 = (const float*)d_in[2];
    const float* b1 = (const float*)d_in[3];
    const float* w2 = (const float*)d_in[4];
    const float* b2 = (const float*)d_in[5];
    const float* w3 = (const float*)d_in[6];
    const float* b3 = (const float*)d_in[7];
    float* out = (float*)d_out;

    half_t* w1t  = (half_t*)d_ws;                    // 4 MB
    half_t* h1h  = w1t + (size_t)H_ * D_;            // 32 MB
    half_t* w2th = h1h + (size_t)M_ * H_;            // 1 MB
    half_t* w2tl = w2th + (size_t)H2_ * H_;          // 1 MB
    float*  cl_acc = (float*)(w2tl + (size_t)H2_ * H_);  // 4 KB
    int* experts_ws = (int*)(cl_acc + B_ * C_ * E_);

    hipMemsetAsync(cl_acc, 0, (size_t)B_ * C_ * E_ * sizeof(float), stream);

    transpose_f16_kernel<<<dim3(H_ / 32, D_ / 32), dim3(256), 0, stream>>>(w1, w1t, D_, H_);
    transpose_split_kernel<<<dim3(H2_ / 32, H_ / 32), dim3(256), 0, stream>>>(w2, w2th, w2tl, H_, H2_);
    gemm1_kernel<<<dim3(H_ / 128, M_ / 128), dim3(256), 0, stream>>>(x, w1t, b1, h1h);
    gemm2_fused_kernel<<<dim3(H2_ / 128, M_ / 128), dim3(256), 0, stream>>>(
        h1h, w2th, w2tl, b2, w3, cl_acc);
    finalize_kernel<<<dim3(1), dim3(128), 0, stream>>>(cl_acc, b3, out, experts_ws);
    routing_weights_kernel<<<dim3(M_ / 256), dim3(256), 0, stream>>>(experts_ws, out + OUT_RW);
}

// Round 6
// 364.904 us; speedup vs baseline: 3.1993x; 1.0064x over previous
//
#include <hip/hip_runtime.h>
#include <math.h>

typedef _Float16 half_t;
typedef __attribute__((ext_vector_type(8))) _Float16 half8v;
typedef __attribute__((ext_vector_type(4))) float floatx4;

constexpr int B_ = 4, S_ = 4096, D_ = 2048, H_ = 1024, H2_ = 512, E_ = 8;
constexpr int CHUNK_ = 128;
constexpr int C_ = S_ / CHUNK_;          // 32
constexpr int M_ = B_ * S_;              // 16384
constexpr float TAU_ = 0.7f;
// Precision ledger (measured): full split absmax=0 (R2); A+W1 pure-f16,
// W2 split kept -> absmax=1.95e-3 = 2^-9 (R4/R5), 60x under threshold.
// W2 residual kept because h1>=0 (positive mean) makes W2-rounding coherent
// across the chunk mean; x/W1 rounding is token-incoherent -> averages out.
constexpr float WSCALE = 64.0f, OSCALE = 1.0f / 64.0f;

constexpr int OUT_RW = 0;
constexpr int OUT_EI = OUT_RW + B_ * S_ * E_;
constexpr int OUT_CL = OUT_EI + B_ * C_;
constexpr int OUT_GE = OUT_CL + B_ * C_ * E_;
constexpr int OUT_UT = OUT_GE + 1;
constexpr int OUT_FR = OUT_UT + E_;
constexpr int OUT_RC = OUT_FR + 1;

// ---------------------------------------------------------------------------
// Prep (one launch): w1 transpose->f16 [2048 blks] | w2 transpose+split
// [512 blks] | cl_acc zero [1 blk].
// ---------------------------------------------------------------------------
__global__ __launch_bounds__(256)
void prep_kernel(const float* __restrict__ w1, const float* __restrict__ w2,
                 half_t* __restrict__ w1t, half_t* __restrict__ w2th,
                 half_t* __restrict__ w2tl, float* __restrict__ cl_acc)
{
    __shared__ float tile[32][33];
    const int tx = threadIdx.x & 31;
    const int ty = threadIdx.x >> 5;
    const int bid = blockIdx.x;

    if (bid < 2048) {                     // w1: [D_,H_] -> w1t [H_,D_] f16
        const int n0 = (bid & 31) * 32;   // H_/32 = 32
        const int k0 = (bid >> 5) * 32;   // D_/32 = 64
#pragma unroll
        for (int r = 0; r < 4; ++r)
            tile[ty + r * 8][tx] = w1[(size_t)(k0 + ty + r * 8) * H_ + n0 + tx];
        __syncthreads();
#pragma unroll
        for (int r = 0; r < 4; ++r)
            w1t[(size_t)(n0 + ty + r * 8) * D_ + k0 + tx] = (half_t)tile[tx][ty + r * 8];
    } else if (bid < 2560) {              // w2: [H_,H2_] -> split hi/lo [H2_,H_]
        const int b2 = bid - 2048;
        const int n0 = (b2 & 15) * 32;    // H2_/32 = 16
        const int k0 = (b2 >> 4) * 32;    // H_/32 = 32
#pragma unroll
        for (int r = 0; r < 4; ++r)
            tile[ty + r * 8][tx] = w2[(size_t)(k0 + ty + r * 8) * H2_ + n0 + tx];
        __syncthreads();
#pragma unroll
        for (int r = 0; r < 4; ++r) {
            const float v = tile[tx][ty + r * 8] * WSCALE;
            const half_t h = (half_t)v;
            const size_t off = (size_t)(n0 + ty + r * 8) * H_ + k0 + tx;
            w2th[off] = h;
            w2tl[off] = (half_t)(v - (float)h);
        }
    } else {                              // zero chunk-logit accumulator
        for (int i = threadIdx.x; i < B_ * C_ * E_; i += 256) cl_acc[i] = 0.0f;
    }
}

// ---------------------------------------------------------------------------
// GEMM1: h1 = relu(x @ w1 + b1) -> f16. Pure f16 MFMA, 128x128 tile, BK=32.
// A: fp32 global->VGPR prefetched ONE ITER AHEAD so its drain rides barrier2
// together with B's global_load_lds (one latency exposure per iter, not two).
// ---------------------------------------------------------------------------
__global__ __launch_bounds__(256, 3)
void gemm1_kernel(const float* __restrict__ X,
                  const half_t* __restrict__ BTh,
                  const float* __restrict__ bias, half_t* __restrict__ outh)
{
    constexpr int KD = D_, ND = H_, BK = 32;
    __shared__ __align__(16) half_t sA[128 * BK];
    __shared__ __align__(16) half_t sB[128 * BK];

    const int tid = threadIdx.x;
    const int lane = tid & 63;
    const int wave = tid >> 6;
    const int wm = (wave & 1) * 64;
    const int wn = (wave >> 1) * 64;
    // XCD swizzle: d=by*8+bx -> xcd=bx owns an M-stripe; 8 consecutive by
    // share one A row-block in that XCD's L2.
    const int rowBlk = blockIdx.x * 16 + (blockIdx.y >> 3);
    const int colBlk = blockIdx.y & 7;
    const long blockM = (long)rowBlk * 128;
    const long blockN = (long)colBlk * 128;

    floatx4 acc[4][4];
#pragma unroll
    for (int i = 0; i < 4; ++i)
#pragma unroll
        for (int j = 0; j < 4; ++j) acc[i][j] = (floatx4){0.f, 0.f, 0.f, 0.f};

    const int srow = tid >> 2;            // 0..63
    const int skoff = (tid & 3) * 8;      // element offset within K-tile
    const int ldsoff = srow * BK + skoff;
    const int fr = lane & 15;
    const int fq = (lane >> 4) * 8;

    const float* Xrow0 = X + (size_t)(blockM + srow) * KD + skoff;
    const float* Xrow1 = Xrow0 + (size_t)64 * KD;

    // prime the pipeline: A(k=0)
    float4 a00 = *(const float4*)(Xrow0);
    float4 a01 = *(const float4*)(Xrow0 + 4);
    float4 a10 = *(const float4*)(Xrow1);
    float4 a11 = *(const float4*)(Xrow1 + 4);

    for (int k0 = 0; k0 < KD; k0 += BK) {
        __syncthreads();                  // prev iter's LDS reads done; nothing in flight
        // B(k0): direct global->LDS (queued)
#pragma unroll
        for (int p = 0; p < 2; ++p) {
            const size_t boff = (size_t)(blockN + srow + p * 64) * KD + k0 + skoff;
            __builtin_amdgcn_global_load_lds(
                (const __attribute__((address_space(1))) void*)(BTh + boff),
                (__attribute__((address_space(3))) void*)(sB + ldsoff + p * 2048), 16, 0, 0);
        }
        // A(k0): cvt regs (loaded last iter) -> LDS
        half8v h0, h1v;
        h0.s0 = (half_t)a00.x; h0.s1 = (half_t)a00.y; h0.s2 = (half_t)a00.z; h0.s3 = (half_t)a00.w;
        h0.s4 = (half_t)a01.x; h0.s5 = (half_t)a01.y; h0.s6 = (half_t)a01.z; h0.s7 = (half_t)a01.w;
        h1v.s0 = (half_t)a10.x; h1v.s1 = (half_t)a10.y; h1v.s2 = (half_t)a10.z; h1v.s3 = (half_t)a10.w;
        h1v.s4 = (half_t)a11.x; h1v.s5 = (half_t)a11.y; h1v.s6 = (half_t)a11.z; h1v.s7 = (half_t)a11.w;
        *(half8v*)(sA + ldsoff) = h0;
        *(half8v*)(sA + ldsoff + 2048) = h1v;
        // A(k0+BK): prefetch — drains together with B at barrier2
        const int kn = (k0 + BK < KD) ? (k0 + BK) : 0;
        a00 = *(const float4*)(Xrow0 + kn);
        a01 = *(const float4*)(Xrow0 + kn + 4);
        a10 = *(const float4*)(Xrow1 + kn);
        a11 = *(const float4*)(Xrow1 + kn + 4);
        __syncthreads();                  // drains B lds-loads + A prefetch together

        half8v fb[4];
#pragma unroll
        for (int t = 0; t < 4; ++t)
            fb[t] = *(const half8v*)(sB + (wn + t * 16 + fr) * BK + fq);
#pragma unroll
        for (int i = 0; i < 4; ++i) {
            const half8v fa = *(const half8v*)(sA + (wm + i * 16 + fr) * BK + fq);
#pragma unroll
            for (int j = 0; j < 4; ++j)
                acc[i][j] = __builtin_amdgcn_mfma_f32_16x16x32_f16(fa, fb[j], acc[i][j], 0, 0, 0);
        }
    }

    const int orow = (lane >> 4) * 4;
    const int ocol = lane & 15;
#pragma unroll
    for (int j = 0; j < 4; ++j) {
        const long gn = blockN + wn + j * 16 + ocol;
        const float bj = bias[gn];
#pragma unroll
        for (int i = 0; i < 4; ++i) {
#pragma unroll
            for (int r = 0; r < 4; ++r) {
                const float v = fmaxf(acc[i][j][r] + bj, 0.0f);
                const size_t off = (size_t)(blockM + wm + i * 16 + orow + r) * ND + gn;
                outh[off] = (half_t)v;
            }
        }
    }
}

// ---------------------------------------------------------------------------
// GEMM2 fused: relu(h1 @ w2 + b2) @ w3, chunk-summed into cl_acc via
// device-scope atomics. h2 never materialized. f16x2 (W2 split kept).
// ---------------------------------------------------------------------------
__global__ __launch_bounds__(256, 3)
void gemm2_fused_kernel(const half_t* __restrict__ Ah,
                        const half_t* __restrict__ BTh, const half_t* __restrict__ BTl,
                        const float* __restrict__ bias, const float* __restrict__ w3,
                        float* __restrict__ cl_acc)
{
    constexpr int KD = H_, BK = 32;
    __shared__ __align__(16) half_t sAh[128 * BK];
    __shared__ __align__(16) half_t sBh[128 * BK];
    __shared__ __align__(16) half_t sBl[128 * BK];

    const int tid = threadIdx.x;
    const int lane = tid & 63;
    const int wave = tid >> 6;
    const int wm = (wave & 1) * 64;
    const int wn = (wave >> 1) * 64;
    const int d = blockIdx.y * 4 + blockIdx.x;
    const int xcd = d & 7;
    const int l = d >> 3;
    const int rowBlk = xcd * 16 + (l >> 2);
    const int colBlk = l & 3;
    const long blockM = (long)rowBlk * 128;
    const long blockN = (long)colBlk * 128;

    floatx4 acc[4][4];
#pragma unroll
    for (int i = 0; i < 4; ++i)
#pragma unroll
        for (int j = 0; j < 4; ++j) acc[i][j] = (floatx4){0.f, 0.f, 0.f, 0.f};

    const int srow = tid >> 2;
    const int skoff = (tid & 3) * 8;
    const int ldsoff = srow * BK + skoff;
    const int fr = lane & 15;
    const int fq = (lane >> 4) * 8;

    for (int k0 = 0; k0 < KD; k0 += BK) {
        __syncthreads();
#pragma unroll
        for (int p = 0; p < 2; ++p) {
            const int row = srow + p * 64;
            const size_t aoff = (size_t)(blockM + row) * KD + k0 + skoff;
            const size_t boff = (size_t)(blockN + row) * KD + k0 + skoff;
            const int loff = ldsoff + p * 2048;
            __builtin_amdgcn_global_load_lds(
                (const __attribute__((address_space(1))) void*)(Ah + aoff),
                (__attribute__((address_space(3))) void*)(sAh + loff), 16, 0, 0);
            __builtin_amdgcn_global_load_lds(
                (const __attribute__((address_space(1))) void*)(BTh + boff),
                (__attribute__((address_space(3))) void*)(sBh + loff), 16, 0, 0);
            __builtin_amdgcn_global_load_lds(
                (const __attribute__((address_space(1))) void*)(BTl + boff),
                (__attribute__((address_space(3))) void*)(sBl + loff), 16, 0, 0);
        }
        __syncthreads();

        half8v fbh[4], fbl[4];
#pragma unroll
        for (int t = 0; t < 4; ++t) {
            fbh[t] = *(const half8v*)(sBh + (wn + t * 16 + fr) * BK + fq);
            fbl[t] = *(const half8v*)(sBl + (wn + t * 16 + fr) * BK + fq);
        }
#pragma unroll
        for (int i = 0; i < 4; ++i) {
            const half8v fah = *(const half8v*)(sAh + (wm + i * 16 + fr) * BK + fq);
#pragma unroll
            for (int j = 0; j < 4; ++j) {
                acc[i][j] = __builtin_amdgcn_mfma_f32_16x16x32_f16(fah, fbh[j], acc[i][j], 0, 0, 0);
                acc[i][j] = __builtin_amdgcn_mfma_f32_16x16x32_f16(fah, fbl[j], acc[i][j], 0, 0, 0);
            }
        }
    }

    const int ocol = lane & 15;
    float p[E_];
#pragma unroll
    for (int e = 0; e < E_; ++e) p[e] = 0.0f;
#pragma unroll
    for (int j = 0; j < 4; ++j) {
        const int gn = (int)blockN + wn + j * 16 + ocol;
        const float bj = bias[gn];
        const float4 w3a = *(const float4*)(w3 + (size_t)gn * E_);
        const float4 w3b = *(const float4*)(w3 + (size_t)gn * E_ + 4);
        float colsum = 0.0f;
#pragma unroll
        for (int i = 0; i < 4; ++i)
#pragma unroll
            for (int r = 0; r < 4; ++r)
                colsum += fmaxf(acc[i][j][r] * OSCALE + bj, 0.0f);
        p[0] += colsum * w3a.x; p[1] += colsum * w3a.y;
        p[2] += colsum * w3a.z; p[3] += colsum * w3a.w;
        p[4] += colsum * w3b.x; p[5] += colsum * w3b.y;
        p[6] += colsum * w3b.z; p[7] += colsum * w3b.w;
    }
#pragma unroll
    for (int e = 0; e < E_; ++e)
#pragma unroll
        for (int off = 32; off > 0; off >>= 1)
            p[e] += __shfl_xor(p[e], off);
#pragma unroll
    for (int e = 0; e < E_; ++e)
        if (lane == e) atomicAdd(&cl_acc[rowBlk * E_ + e], p[e]);
}

// ---------------------------------------------------------------------------
// Final+route (one launch, 64 blocks): every block redundantly computes the
// chunk logits (4 KB), argmax, and hysteresis scan (cheap), then writes its
// 256-token slice of routing_weights. Block 0 additionally writes EI/CL/stats.
// prev_expert_indices is dead in the reference (scan init zeros + is_first).
// ---------------------------------------------------------------------------
__global__ __launch_bounds__(256)
void final_route_kernel(const float* __restrict__ cl_acc, const float* __restrict__ b3,
                        float* __restrict__ out)
{
    __shared__ float cl[B_ * C_][E_];
    __shared__ int tops[B_ * C_];
    __shared__ int finals[B_ * C_];
    __shared__ int flips[B_];
    __shared__ float ent[B_ * C_];

    const int tid = threadIdx.x;

    if (tid < B_ * C_) {
        int best = 0;
        float bvv = -1e30f;
#pragma unroll
        for (int e = 0; e < E_; ++e) {
            const float v = cl_acc[tid * E_ + e] * (1.0f / CHUNK_) + b3[e];
            cl[tid][e] = v;
            if (v > bvv) { bvv = v; best = e; }   // first-max tiebreak == np.argmax
        }
        tops[tid] = best;
    }
    __syncthreads();

    if (tid < B_) {
        const int b = tid;
        int prev = 0, fl = 0;
        for (int c = 0; c < C_; ++c) {
            const int t = tops[b * C_ + c];
            int fin;
            if (c == 0) {
                fin = t;
            } else {
                const float cur = cl[b * C_ + c][t];
                const float pv = cl[b * C_ + c][prev];
                const bool sw = (cur - pv) > TAU_;
                if (sw) fl++;
                fin = sw ? t : prev;
            }
            finals[b * C_ + c] = fin;
            prev = fin;
        }
        flips[b] = fl;
    }
    __syncthreads();

    // routing_weights slice: 256 tokens per block
    {
        const int tok = blockIdx.x * 256 + tid;
        const int b = tok >> 12;
        const int c = (tok & (S_ - 1)) >> 7;
        const int e = finals[b * C_ + c];
        float4 v0 = make_float4(e == 0 ? 1.f : 0.f, e == 1 ? 1.f : 0.f,
                                e == 2 ? 1.f : 0.f, e == 3 ? 1.f : 0.f);
        float4 v1 = make_float4(e == 4 ? 1.f : 0.f, e == 5 ? 1.f : 0.f,
                                e == 6 ? 1.f : 0.f, e == 7 ? 1.f : 0.f);
        float4* dst = (float4*)(out + OUT_RW + (size_t)tok * E_);
        dst[0] = v0;
        dst[1] = v1;
    }

    if (blockIdx.x == 0) {
        if (tid < B_ * C_) {
            out[OUT_EI + tid] = (float)finals[tid];
#pragma unroll
            for (int e = 0; e < E_; ++e) out[OUT_CL + tid * E_ + e] = cl[tid][e];
            // softmax entropy per chunk
            float m = cl[tid][0];
            for (int e = 1; e < E_; ++e) m = fmaxf(m, cl[tid][e]);
            float pr[E_], s = 0.0f;
            for (int e = 0; e < E_; ++e) { pr[e] = expf(cl[tid][e] - m); s += pr[e]; }
            const float inv = 1.0f / s;
            float h = 0.0f;
            for (int e = 0; e < E_; ++e) { const float pe = pr[e] * inv; h -= pe * logf(pe + 1e-8f); }
            ent[tid] = h;
        }
        __syncthreads();
        if (tid == 0) {
            float esum = 0.0f;
            for (int i = 0; i < B_ * C_; ++i) esum += ent[i];
            out[OUT_GE] = esum / (float)(B_ * C_);

            int cnt[E_];
            for (int e = 0; e < E_; ++e) cnt[e] = 0;
            for (int i = 0; i < B_ * C_; ++i) cnt[finals[i]]++;
            float n2 = 0.0f;
            for (int e = 0; e < E_; ++e) {
                const float u = (float)cnt[e] / (float)(B_ * C_);
                out[OUT_UT + e] = u;
                n2 += u * u;
            }
            const int totfl = flips[0] + flips[1] + flips[2] + flips[3];
            out[OUT_FR] = (float)totfl / (float)(B_ * (C_ - 1));
            out[OUT_RC] = sqrtf(n2);
        }
    }
}

// ---------------------------------------------------------------------------
extern "C" void kernel_launch(void* const* d_in, const int* in_sizes, int n_in,
                              void* d_out, int out_size, void* d_ws, size_t ws_size,
                              hipStream_t stream)
{
    const float* x  = (const float*)d_in[0];
    const float* w1 = (const float*)d_in[2];
    const float* b1 = (const float*)d_in[3];
    const float* w2 = (const float*)d_in[4];
    const float* b2 = (const float*)d_in[5];
    const float* w3 = (const float*)d_in[6];
    const float* b3 = (const float*)d_in[7];
    float* out = (float*)d_out;

    half_t* w1t  = (half_t*)d_ws;                    // 4 MB
    half_t* h1h  = w1t + (size_t)H_ * D_;            // 32 MB
    half_t* w2th = h1h + (size_t)M_ * H_;            // 1 MB
    half_t* w2tl = w2th + (size_t)H2_ * H_;          // 1 MB
    float*  cl_acc = (float*)(w2tl + (size_t)H2_ * H_);  // 4 KB

    // 1) prep: transposes + cl_acc zero (one launch)
    prep_kernel<<<dim3(2561), dim3(256), 0, stream>>>(w1, w2, w1t, w2th, w2tl, cl_acc);
    // 2) GEMM1 (pure f16, A-prefetch pipelined)
    gemm1_kernel<<<dim3(H_ / 128, M_ / 128), dim3(256), 0, stream>>>(x, w1t, b1, h1h);
    // 3) GEMM2 fused through layer-3 + chunk-sum
    gemm2_fused_kernel<<<dim3(H2_ / 128, M_ / 128), dim3(256), 0, stream>>>(
        h1h, w2th, w2tl, b2, w3, cl_acc);
    // 4) finalize + routing weights (one launch)
    final_route_kernel<<<dim3(M_ / 256), dim3(256), 0, stream>>>(cl_acc, b3, out);
}

// Round 7
// 354.579 us; speedup vs baseline: 3.2925x; 1.0291x over previous
//
#include <hip/hip_runtime.h>
#include <math.h>

typedef _Float16 half_t;
typedef __attribute__((ext_vector_type(4))) _Float16 half4v;
typedef __attribute__((ext_vector_type(8))) _Float16 half8v;
typedef __attribute__((ext_vector_type(4))) float floatx4;

constexpr int B_ = 4, S_ = 4096, D_ = 2048, H_ = 1024, H2_ = 512, E_ = 8;
constexpr int CHUNK_ = 128;
constexpr int C_ = S_ / CHUNK_;          // 32
constexpr int M_ = B_ * S_;              // 16384
constexpr float TAU_ = 0.7f;
// Precision ledger (measured): full split absmax=0 (R2); x/W1 pure-f16 +
// W2 split kept -> absmax = 2^-9 (R4-R6), 60x under threshold. W2 residual
// kept: h1>=0 (positive mean) makes W2-rounding coherent through the chunk
// mean; x/W1 rounding is token-incoherent -> averages out ~sqrt(128).
constexpr float WSCALE = 64.0f, OSCALE = 1.0f / 64.0f;

constexpr int OUT_RW = 0;
constexpr int OUT_EI = OUT_RW + B_ * S_ * E_;
constexpr int OUT_CL = OUT_EI + B_ * C_;
constexpr int OUT_GE = OUT_CL + B_ * C_ * E_;
constexpr int OUT_UT = OUT_GE + 1;
constexpr int OUT_FR = OUT_UT + E_;
constexpr int OUT_RC = OUT_FR + 1;

// ---------------------------------------------------------------------------
// Prep (one launch):
//   blocks [0,8192):       x fp32 -> f16 (1024 float4 per block)
//   blocks [8192,10240):   w1 [D,H] -> w1t [H,D] f16
//   blocks [10240,10752):  w2 [H,H2] -> w2t hi/lo [H2,H], pre-scaled x64
//   block  10752:          zero cl_acc
// ---------------------------------------------------------------------------
__global__ __launch_bounds__(256)
void prep_kernel(const float* __restrict__ x, const float* __restrict__ w1,
                 const float* __restrict__ w2,
                 half_t* __restrict__ xh, half_t* __restrict__ w1t,
                 half_t* __restrict__ w2th, half_t* __restrict__ w2tl,
                 float* __restrict__ cl_acc)
{
    __shared__ float tile[32][33];
    const int tx = threadIdx.x & 31;
    const int ty = threadIdx.x >> 5;
    const int bid = blockIdx.x;

    if (bid < 8192) {                     // convert x: 1024 float4 per block
        const int base = bid * 1024 + threadIdx.x;
#pragma unroll
        for (int p = 0; p < 4; ++p) {
            const int i = base + p * 256;
            const float4 v = ((const float4*)x)[i];
            half4v h;
            h.x = (half_t)v.x; h.y = (half_t)v.y; h.z = (half_t)v.z; h.w = (half_t)v.w;
            ((half4v*)xh)[i] = h;
        }
    } else if (bid < 10240) {             // w1 transpose -> f16
        const int b2 = bid - 8192;
        const int n0 = (b2 & 31) * 32;    // H_/32 = 32
        const int k0 = (b2 >> 5) * 32;    // D_/32 = 64
#pragma unroll
        for (int r = 0; r < 4; ++r)
            tile[ty + r * 8][tx] = w1[(size_t)(k0 + ty + r * 8) * H_ + n0 + tx];
        __syncthreads();
#pragma unroll
        for (int r = 0; r < 4; ++r)
            w1t[(size_t)(n0 + ty + r * 8) * D_ + k0 + tx] = (half_t)tile[tx][ty + r * 8];
    } else if (bid < 10752) {             // w2 transpose + split
        const int b2 = bid - 10240;
        const int n0 = (b2 & 15) * 32;    // H2_/32 = 16
        const int k0 = (b2 >> 4) * 32;    // H_/32 = 32
#pragma unroll
        for (int r = 0; r < 4; ++r)
            tile[ty + r * 8][tx] = w2[(size_t)(k0 + ty + r * 8) * H2_ + n0 + tx];
        __syncthreads();
#pragma unroll
        for (int r = 0; r < 4; ++r) {
            const float v = tile[tx][ty + r * 8] * WSCALE;
            const half_t h = (half_t)v;
            const size_t off = (size_t)(n0 + ty + r * 8) * H_ + k0 + tx;
            w2th[off] = h;
            w2tl[off] = (half_t)(v - (float)h);
        }
    } else {                              // zero chunk-logit accumulator
        for (int i = threadIdx.x; i < B_ * C_ * E_; i += 256) cl_acc[i] = 0.0f;
    }
}

// ---------------------------------------------------------------------------
// GEMM1: h1 = relu(xh @ w1 + b1) -> f16. Exact m97 structure: pure f16 MFMA,
// 128x128 tile, BK=32, BOTH streams via global_load_lds(16B), 16 KB LDS,
// XCD-swizzled. No VGPR round-trip in staging (R5/R6's in-kernel cvt halved
// throughput: 443 TF vs this structure's ~850 TF on the same skeleton).
// ---------------------------------------------------------------------------
__global__ __launch_bounds__(256, 3)
void gemm1_kernel(const half_t* __restrict__ Ah,
                  const half_t* __restrict__ BTh,
                  const float* __restrict__ bias, half_t* __restrict__ outh)
{
    constexpr int KD = D_, ND = H_, BK = 32;
    __shared__ __align__(16) half_t sA[128 * BK];
    __shared__ __align__(16) half_t sB[128 * BK];

    const int tid = threadIdx.x;
    const int lane = tid & 63;
    const int wave = tid >> 6;
    const int wm = (wave & 1) * 64;
    const int wn = (wave >> 1) * 64;
    // XCD swizzle: d=by*8+bx -> xcd=bx owns an M-stripe; 8 consecutive by
    // share one A row-block in that XCD's L2.
    const int rowBlk = blockIdx.x * 16 + (blockIdx.y >> 3);
    const int colBlk = blockIdx.y & 7;
    const long blockM = (long)rowBlk * 128;
    const long blockN = (long)colBlk * 128;

    floatx4 acc[4][4];
#pragma unroll
    for (int i = 0; i < 4; ++i)
#pragma unroll
        for (int j = 0; j < 4; ++j) acc[i][j] = (floatx4){0.f, 0.f, 0.f, 0.f};

    const int srow = tid >> 2;            // 0..63
    const int skoff = (tid & 3) * 8;
    const int ldsoff = srow * BK + skoff;
    const int fr = lane & 15;
    const int fq = (lane >> 4) * 8;

    for (int k0 = 0; k0 < KD; k0 += BK) {
        __syncthreads();
#pragma unroll
        for (int p = 0; p < 2; ++p) {
            const int row = srow + p * 64;
            const size_t aoff = (size_t)(blockM + row) * KD + k0 + skoff;
            const size_t boff = (size_t)(blockN + row) * KD + k0 + skoff;
            const int loff = ldsoff + p * 2048;
            __builtin_amdgcn_global_load_lds(
                (const __attribute__((address_space(1))) void*)(Ah + aoff),
                (__attribute__((address_space(3))) void*)(sA + loff), 16, 0, 0);
            __builtin_amdgcn_global_load_lds(
                (const __attribute__((address_space(1))) void*)(BTh + boff),
                (__attribute__((address_space(3))) void*)(sB + loff), 16, 0, 0);
        }
        __syncthreads();

        half8v fb[4];
#pragma unroll
        for (int t = 0; t < 4; ++t)
            fb[t] = *(const half8v*)(sB + (wn + t * 16 + fr) * BK + fq);
#pragma unroll
        for (int i = 0; i < 4; ++i) {
            const half8v fa = *(const half8v*)(sA + (wm + i * 16 + fr) * BK + fq);
#pragma unroll
            for (int j = 0; j < 4; ++j)
                acc[i][j] = __builtin_amdgcn_mfma_f32_16x16x32_f16(fa, fb[j], acc[i][j], 0, 0, 0);
        }
    }

    const int orow = (lane >> 4) * 4;
    const int ocol = lane & 15;
#pragma unroll
    for (int j = 0; j < 4; ++j) {
        const long gn = blockN + wn + j * 16 + ocol;
        const float bj = bias[gn];
#pragma unroll
        for (int i = 0; i < 4; ++i) {
#pragma unroll
            for (int r = 0; r < 4; ++r) {
                const float v = fmaxf(acc[i][j][r] + bj, 0.0f);
                const size_t off = (size_t)(blockM + wm + i * 16 + orow + r) * ND + gn;
                outh[off] = (half_t)v;
            }
        }
    }
}

// ---------------------------------------------------------------------------
// GEMM2 fused: relu(h1 @ w2 + b2) @ w3, chunk-summed into cl_acc via
// device-scope atomics. h2 never materialized. f16x2 (W2 split kept).
// ---------------------------------------------------------------------------
__global__ __launch_bounds__(256, 3)
void gemm2_fused_kernel(const half_t* __restrict__ Ah,
                        const half_t* __restrict__ BTh, const half_t* __restrict__ BTl,
                        const float* __restrict__ bias, const float* __restrict__ w3,
                        float* __restrict__ cl_acc)
{
    constexpr int KD = H_, BK = 32;
    __shared__ __align__(16) half_t sAh[128 * BK];
    __shared__ __align__(16) half_t sBh[128 * BK];
    __shared__ __align__(16) half_t sBl[128 * BK];

    const int tid = threadIdx.x;
    const int lane = tid & 63;
    const int wave = tid >> 6;
    const int wm = (wave & 1) * 64;
    const int wn = (wave >> 1) * 64;
    const int d = blockIdx.y * 4 + blockIdx.x;
    const int xcd = d & 7;
    const int l = d >> 3;
    const int rowBlk = xcd * 16 + (l >> 2);
    const int colBlk = l & 3;
    const long blockM = (long)rowBlk * 128;
    const long blockN = (long)colBlk * 128;

    floatx4 acc[4][4];
#pragma unroll
    for (int i = 0; i < 4; ++i)
#pragma unroll
        for (int j = 0; j < 4; ++j) acc[i][j] = (floatx4){0.f, 0.f, 0.f, 0.f};

    const int srow = tid >> 2;
    const int skoff = (tid & 3) * 8;
    const int ldsoff = srow * BK + skoff;
    const int fr = lane & 15;
    const int fq = (lane >> 4) * 8;

    for (int k0 = 0; k0 < KD; k0 += BK) {
        __syncthreads();
#pragma unroll
        for (int p = 0; p < 2; ++p) {
            const int row = srow + p * 64;
            const size_t aoff = (size_t)(blockM + row) * KD + k0 + skoff;
            const size_t boff = (size_t)(blockN + row) * KD + k0 + skoff;
            const int loff = ldsoff + p * 2048;
            __builtin_amdgcn_global_load_lds(
                (const __attribute__((address_space(1))) void*)(Ah + aoff),
                (__attribute__((address_space(3))) void*)(sAh + loff), 16, 0, 0);
            __builtin_amdgcn_global_load_lds(
                (const __attribute__((address_space(1))) void*)(BTh + boff),
                (__attribute__((address_space(3))) void*)(sBh + loff), 16, 0, 0);
            __builtin_amdgcn_global_load_lds(
                (const __attribute__((address_space(1))) void*)(BTl + boff),
                (__attribute__((address_space(3))) void*)(sBl + loff), 16, 0, 0);
        }
        __syncthreads();

        half8v fbh[4], fbl[4];
#pragma unroll
        for (int t = 0; t < 4; ++t) {
            fbh[t] = *(const half8v*)(sBh + (wn + t * 16 + fr) * BK + fq);
            fbl[t] = *(const half8v*)(sBl + (wn + t * 16 + fr) * BK + fq);
        }
#pragma unroll
        for (int i = 0; i < 4; ++i) {
            const half8v fah = *(const half8v*)(sAh + (wm + i * 16 + fr) * BK + fq);
#pragma unroll
            for (int j = 0; j < 4; ++j) {
                acc[i][j] = __builtin_amdgcn_mfma_f32_16x16x32_f16(fah, fbh[j], acc[i][j], 0, 0, 0);
                acc[i][j] = __builtin_amdgcn_mfma_f32_16x16x32_f16(fah, fbl[j], acc[i][j], 0, 0, 0);
            }
        }
    }

    const int ocol = lane & 15;
    float p[E_];
#pragma unroll
    for (int e = 0; e < E_; ++e) p[e] = 0.0f;
#pragma unroll
    for (int j = 0; j < 4; ++j) {
        const int gn = (int)blockN + wn + j * 16 + ocol;
        const float bj = bias[gn];
        const float4 w3a = *(const float4*)(w3 + (size_t)gn * E_);
        const float4 w3b = *(const float4*)(w3 + (size_t)gn * E_ + 4);
        float colsum = 0.0f;
#pragma unroll
        for (int i = 0; i < 4; ++i)
#pragma unroll
            for (int r = 0; r < 4; ++r)
                colsum += fmaxf(acc[i][j][r] * OSCALE + bj, 0.0f);
        p[0] += colsum * w3a.x; p[1] += colsum * w3a.y;
        p[2] += colsum * w3a.z; p[3] += colsum * w3a.w;
        p[4] += colsum * w3b.x; p[5] += colsum * w3b.y;
        p[6] += colsum * w3b.z; p[7] += colsum * w3b.w;
    }
#pragma unroll
    for (int e = 0; e < E_; ++e)
#pragma unroll
        for (int off = 32; off > 0; off >>= 1)
            p[e] += __shfl_xor(p[e], off);
#pragma unroll
    for (int e = 0; e < E_; ++e)
        if (lane == e) atomicAdd(&cl_acc[rowBlk * E_ + e], p[e]);
}

// ---------------------------------------------------------------------------
// Final+route (one launch, 64 blocks): every block redundantly computes the
// chunk logits, argmax, and hysteresis scan, then writes its routing-weight
// slice. Block 0 additionally writes EI/CL/stats.
// prev_expert_indices is dead in the reference (scan init zeros + is_first).
// ---------------------------------------------------------------------------
__global__ __launch_bounds__(256)
void final_route_kernel(const float* __restrict__ cl_acc, const float* __restrict__ b3,
                        float* __restrict__ out)
{
    __shared__ float cl[B_ * C_][E_];
    __shared__ int tops[B_ * C_];
    __shared__ int finals[B_ * C_];
    __shared__ int flips[B_];
    __shared__ float ent[B_ * C_];

    const int tid = threadIdx.x;

    if (tid < B_ * C_) {
        int best = 0;
        float bvv = -1e30f;
#pragma unroll
        for (int e = 0; e < E_; ++e) {
            const float v = cl_acc[tid * E_ + e] * (1.0f / CHUNK_) + b3[e];
            cl[tid][e] = v;
            if (v > bvv) { bvv = v; best = e; }   // first-max tiebreak == np.argmax
        }
        tops[tid] = best;
    }
    __syncthreads();

    if (tid < B_) {
        const int b = tid;
        int prev = 0, fl = 0;
        for (int c = 0; c < C_; ++c) {
            const int t = tops[b * C_ + c];
            int fin;
            if (c == 0) {
                fin = t;
            } else {
                const float cur = cl[b * C_ + c][t];
                const float pv = cl[b * C_ + c][prev];
                const bool sw = (cur - pv) > TAU_;
                if (sw) fl++;
                fin = sw ? t : prev;
            }
            finals[b * C_ + c] = fin;
            prev = fin;
        }
        flips[b] = fl;
    }
    __syncthreads();

    {
        const int tok = blockIdx.x * 256 + tid;
        const int b = tok >> 12;
        const int c = (tok & (S_ - 1)) >> 7;
        const int e = finals[b * C_ + c];
        float4 v0 = make_float4(e == 0 ? 1.f : 0.f, e == 1 ? 1.f : 0.f,
                                e == 2 ? 1.f : 0.f, e == 3 ? 1.f : 0.f);
        float4 v1 = make_float4(e == 4 ? 1.f : 0.f, e == 5 ? 1.f : 0.f,
                                e == 6 ? 1.f : 0.f, e == 7 ? 1.f : 0.f);
        float4* dst = (float4*)(out + OUT_RW + (size_t)tok * E_);
        dst[0] = v0;
        dst[1] = v1;
    }

    if (blockIdx.x == 0) {
        if (tid < B_ * C_) {
            out[OUT_EI + tid] = (float)finals[tid];
#pragma unroll
            for (int e = 0; e < E_; ++e) out[OUT_CL + tid * E_ + e] = cl[tid][e];
            float m = cl[tid][0];
            for (int e = 1; e < E_; ++e) m = fmaxf(m, cl[tid][e]);
            float pr[E_], s = 0.0f;
            for (int e = 0; e < E_; ++e) { pr[e] = expf(cl[tid][e] - m); s += pr[e]; }
            const float inv = 1.0f / s;
            float h = 0.0f;
            for (int e = 0; e < E_; ++e) { const float pe = pr[e] * inv; h -= pe * logf(pe + 1e-8f); }
            ent[tid] = h;
        }
        __syncthreads();
        if (tid == 0) {
            float esum = 0.0f;
            for (int i = 0; i < B_ * C_; ++i) esum += ent[i];
            out[OUT_GE] = esum / (float)(B_ * C_);

            int cnt[E_];
            for (int e = 0; e < E_; ++e) cnt[e] = 0;
            for (int i = 0; i < B_ * C_; ++i) cnt[finals[i]]++;
            float n2 = 0.0f;
            for (int e = 0; e < E_; ++e) {
                const float u = (float)cnt[e] / (float)(B_ * C_);
                out[OUT_UT + e] = u;
                n2 += u * u;
            }
            const int totfl = flips[0] + flips[1] + flips[2] + flips[3];
            out[OUT_FR] = (float)totfl / (float)(B_ * (C_ - 1));
            out[OUT_RC] = sqrtf(n2);
        }
    }
}

// ---------------------------------------------------------------------------
extern "C" void kernel_launch(void* const* d_in, const int* in_sizes, int n_in,
                              void* d_out, int out_size, void* d_ws, size_t ws_size,
                              hipStream_t stream)
{
    const float* x  = (const float*)d_in[0];
    const float* w1 = (const float*)d_in[2];
    const float* b1 = (const float*)d_in[3];
    const float* w2 = (const float*)d_in[4];
    const float* b2 = (const float*)d_in[5];
    const float* w3 = (const float*)d_in[6];
    const float* b3 = (const float*)d_in[7];
    float* out = (float*)d_out;

    half_t* xh   = (half_t*)d_ws;                    // 64 MB
    half_t* w1t  = xh + (size_t)M_ * D_;             // 4 MB
    half_t* h1h  = w1t + (size_t)H_ * D_;            // 32 MB
    half_t* w2th = h1h + (size_t)M_ * H_;            // 1 MB
    half_t* w2tl = w2th + (size_t)H2_ * H_;          // 1 MB
    float*  cl_acc = (float*)(w2tl + (size_t)H2_ * H_);  // 4 KB

    // 1) prep: x->f16 convert + transposes + cl_acc zero (one launch)
    prep_kernel<<<dim3(10753), dim3(256), 0, stream>>>(x, w1, w2, xh, w1t, w2th, w2tl, cl_acc);
    // 2) GEMM1 (pure f16, m97 dual global_load_lds staging)
    gemm1_kernel<<<dim3(H_ / 128, M_ / 128), dim3(256), 0, stream>>>(xh, w1t, b1, h1h);
    // 3) GEMM2 fused through layer-3 + chunk-sum
    gemm2_fused_kernel<<<dim3(H2_ / 128, M_ / 128), dim3(256), 0, stream>>>(
        h1h, w2th, w2tl, b2, w3, cl_acc);
    // 4) finalize + routing weights (one launch)
    final_route_kernel<<<dim3(M_ / 256), dim3(256), 0, stream>>>(cl_acc, b3, out);
}